// Round 9
// baseline (235.901 us; speedup 1.0000x reference)
//
#include <hip/hip_runtime.h>
#include <math.h>

#define B_ 2
#define L_ 2048
#define C_ 768
#define H_ 12
#define D_ 64
#define M_ (B_ * L_)          // 4096
#define MAXLOG 4.605170185988091f   // log(100)

typedef __bf16 bf16;
typedef __bf16 bf16x4 __attribute__((ext_vector_type(4)));
typedef __bf16 bf16x8 __attribute__((ext_vector_type(8)));
typedef float  f32x4  __attribute__((ext_vector_type(4)));
typedef short  s16x4  __attribute__((ext_vector_type(4)));

// workspace element counts
#define SZ_  ((size_t)B_ * H_ * L_ * D_)   // 3,145,728 (q,k,vt each)
#define MC_  ((size_t)M_ * C_)             // 3,145,728 (x / ao)
#define WQ_  ((size_t)3 * C_ * C_)         // 1,769,472 (W_qkv)
#define WP_  ((size_t)C_ * C_)             //   589,824 (W_proj)

// K=16 bf16 MFMA. S^T accumulator layout (row=4*quad+reg, col=lane&15) equals
// this op's B-fragment layout, so P^T feeds PV directly from registers.
static __device__ __forceinline__ f32x4 mfma16(bf16x4 a, bf16x4 b, f32x4 c) {
#if __has_builtin(__builtin_amdgcn_mfma_f32_16x16x16_bf16)
    return __builtin_amdgcn_mfma_f32_16x16x16_bf16(a, b, c, 0, 0, 0);
#elif __has_builtin(__builtin_amdgcn_mfma_f32_16x16x16bf16_1k)
    return __builtin_amdgcn_mfma_f32_16x16x16bf16_1k(*(s16x4*)&a, *(s16x4*)&b, c, 0, 0, 0);
#else
    f32x4 d;
    asm("v_mfma_f32_16x16x16_bf16 %0, %1, %2, %3" : "=v"(d) : "v"(a), "v"(b), "v"(c));
    return d;
#endif
}

// 16B async global->LDS stage (GEMMs only; LDS dest linear in lane).
static __device__ __forceinline__ void stage16(const bf16* gsrc, void* ldst) {
#if __has_builtin(__builtin_amdgcn_global_load_lds)
    __builtin_amdgcn_global_load_lds(
        (const __attribute__((address_space(1))) unsigned int*)gsrc,
        (__attribute__((address_space(3))) unsigned int*)ldst, 16, 0, 0);
#else
    *(bf16x8*)ldst = *(const bf16x8*)gsrc;
#endif
}

// ---------------------------------------------------------------------------
// Kernel 0: fused prep (unchanged R7).
// ---------------------------------------------------------------------------
__global__ __launch_bounds__(256) void prep(
    const float4* __restrict__ x, const float4* __restrict__ Wq,
    const float4* __restrict__ Wp,
    bf16* __restrict__ xb, bf16* __restrict__ wqb,
    bf16* __restrict__ Wh, bf16* __restrict__ Wl)
{
    const int X4 = (int)(MC_ / 4);
    const int W4 = (int)(WQ_ / 4);
    const int S4 = (int)(WP_ / 4);
    const int total = X4 + W4 + S4;

    const int i0 = blockIdx.x * 256 + threadIdx.x;
    const int stride = gridDim.x * 256;
    for (int i = i0; i < total; i += stride) {
        if (i < X4) {
            const float4 v = x[i];
            bf16x4 o; o[0]=(bf16)v.x; o[1]=(bf16)v.y; o[2]=(bf16)v.z; o[3]=(bf16)v.w;
            *(bf16x4*)&xb[(size_t)i * 4] = o;
        } else if (i < X4 + W4) {
            const int j = i - X4;
            const float4 v = Wq[j];
            bf16x4 o; o[0]=(bf16)v.x; o[1]=(bf16)v.y; o[2]=(bf16)v.z; o[3]=(bf16)v.w;
            *(bf16x4*)&wqb[(size_t)j * 4] = o;
        } else {
            const int j = i - X4 - W4;
            const float4 v = Wp[j];
            bf16x4 h, l;
            h[0]=(bf16)v.x; l[0]=(bf16)(v.x-(float)h[0]);
            h[1]=(bf16)v.y; l[1]=(bf16)(v.y-(float)h[1]);
            h[2]=(bf16)v.z; l[2]=(bf16)(v.z-(float)h[2]);
            h[3]=(bf16)v.w; l[3]=(bf16)(v.w-(float)h[3]);
            *(bf16x4*)&Wh[(size_t)j * 4] = h;
            *(bf16x4*)&Wl[(size_t)j * 4] = l;
        }
    }
}

// ---------------------------------------------------------------------------
// Kernel 1: QKV GEMM (unchanged R7: DMA staging, linear LDS + XOR swizzle).
// ---------------------------------------------------------------------------
__global__ __launch_bounds__(256) void qkv_mfma(
    const bf16* __restrict__ A, const bf16* __restrict__ W,
    const float* __restrict__ bias, const float* __restrict__ sml,
    bf16* __restrict__ qb, bf16* __restrict__ kb, bf16* __restrict__ vtb)
{
    __shared__ __align__(16) bf16 As[128][64];
    __shared__ __align__(16) bf16 Bs[64][64];

    const int t    = threadIdx.x;
    const int w    = t >> 6;
    const int lane = t & 63;
    const int quad = lane >> 4;
    const int c    = lane & 15;
    const int m0   = blockIdx.x * 128;
    const int n0   = blockIdx.y * 64;

    const int sr = t >> 3;
    const int sc = t & 7;
    const int sx = sc ^ (sr & 7);

    f32x4 acc[2][4];
    #pragma unroll
    for (int mt = 0; mt < 2; ++mt)
        #pragma unroll
        for (int nt = 0; nt < 4; ++nt) acc[mt][nt] = (f32x4){0.f,0.f,0.f,0.f};

    for (int kt = 0; kt < C_; kt += 64) {
        __syncthreads();
        #pragma unroll
        for (int p = 0; p < 4; ++p)
            stage16(&A[(size_t)(m0 + 32 * p + sr) * C_ + kt + 8 * sx],
                    (char*)&As[0][0] + (p * 256 + t) * 16);
        #pragma unroll
        for (int p = 0; p < 2; ++p)
            stage16(&W[(size_t)(n0 + 32 * p + sr) * C_ + kt + 8 * sx],
                    (char*)&Bs[0][0] + (p * 256 + t) * 16);
        __syncthreads();

        #pragma unroll
        for (int ks = 0; ks < 2; ++ks) {
            const int rchunk = ((4 * ks + quad) ^ (c & 7)) * 16;
            #pragma unroll
            for (int mt = 0; mt < 2; ++mt) {
                const bf16x8 a = *(const bf16x8*)((const char*)&As[0][0]
                                 + (size_t)(w * 32 + mt * 16 + c) * 128 + rchunk);
                #pragma unroll
                for (int nt = 0; nt < 4; ++nt) {
                    const bf16x8 b = *(const bf16x8*)((const char*)&Bs[0][0]
                                     + (size_t)(nt * 16 + c) * 128 + rchunk);
                    acc[mt][nt] = __builtin_amdgcn_mfma_f32_16x16x32_bf16(a, b, acc[mt][nt], 0, 0, 0);
                }
            }
        }
    }

    const int three = blockIdx.y / H_;
    const int h     = blockIdx.y % H_;
    const int bidx  = m0 >> 11;
    const int l0    = (m0 & (L_ - 1)) + w * 32;

    if (three < 2) {
        bf16* dst = (three == 0) ? qb : kb;
        const float scale = (three == 0) ? expf(fminf(sml[h], MAXLOG)) : 1.0f;
        #pragma unroll
        for (int mt = 0; mt < 2; ++mt) {
            float val[4][4];
            float ss[4] = {0.f, 0.f, 0.f, 0.f};
            #pragma unroll
            for (int nt = 0; nt < 4; ++nt) {
                const float bb = bias[n0 + nt * 16 + c];
                #pragma unroll
                for (int reg = 0; reg < 4; ++reg) {
                    const float v = acc[mt][nt][reg] + bb;
                    val[nt][reg] = v;
                    ss[reg] += v * v;
                }
            }
            #pragma unroll
            for (int reg = 0; reg < 4; ++reg) {
                float s = ss[reg];
                #pragma unroll
                for (int off = 1; off < 16; off <<= 1) s += __shfl_xor(s, off, 16);
                const float inv = scale / fmaxf(sqrtf(s), 1e-12f);
                const int l = l0 + mt * 16 + quad * 4 + reg;
                #pragma unroll
                for (int nt = 0; nt < 4; ++nt)
                    dst[((size_t)(bidx * H_ + h) * L_ + l) * D_ + nt * 16 + c] =
                        (bf16)(val[nt][reg] * inv);
            }
        }
    } else {
        #pragma unroll
        for (int mt = 0; mt < 2; ++mt)
            #pragma unroll
            for (int nt = 0; nt < 4; ++nt) {
                const int d = nt * 16 + c;
                const float bb = bias[n0 + d];
                const int l = l0 + mt * 16 + quad * 4;
                bf16x4 o;
                #pragma unroll
                for (int reg = 0; reg < 4; ++reg) o[reg] = (bf16)(acc[mt][nt][reg] + bb);
                *(bf16x4*)&vtb[((size_t)(bidx * H_ + h) * D_ + d) * L_ + l] = o;
            }
    }
}

// ---------------------------------------------------------------------------
// Kernel 2: flash attention v11 — wave = 32q (2 q-tiles, K/V frag reuse)
//   x 1024-k half. Waves (wq,wk): wq picks q-half, wk picks k-half.
//   BK=32 tiles, double-buffered (v7 1-barrier/step skeleton, 32 barriers).
//   Each K/V byte read by 2 waves (was 4) -> block LDS read traffic halved
//   at unchanged occupancy (768 blocks, 3/CU, 12 waves/CU).
//   k-halves merged in-block through LDS (v6-proven epilogue).
// ---------------------------------------------------------------------------
__global__ __launch_bounds__(256, 3) void flash_mfma(
    const bf16* __restrict__ q, const bf16* __restrict__ k,
    const bf16* __restrict__ vt, const float* __restrict__ bias,
    const float* __restrict__ sml,
    bf16* __restrict__ aoh, bf16* __restrict__ aol)
{
    __shared__ __align__(16) bf16 Klds[2][2][32][72];   // [half][buf][krow][d] 18 KB
    __shared__ __align__(16) bf16 Vlds[2][2][64][36];   // [half][buf][drow][k] 18 KB
    __shared__ __align__(16) float OfT[2][2][4][64][4]; // [wq][qt][dt][lane][r] 16 KB
    __shared__ float lfs[2][2][16];

    const int t    = threadIdx.x;
    const int w    = t >> 6;
    const int lane = t & 63;
    const int quad = lane >> 4;
    const int c    = lane & 15;
    const int wq   = w >> 1;
    const int wk   = w & 1;
    const int q0   = blockIdx.x * 64;
    const int bh   = blockIdx.y;
    const int h    = bh % H_;
    const int b    = bh / H_;
    const size_t base  = (size_t)bh * L_ * D_;
    const size_t vbase = (size_t)bh * D_ * L_;
    const int koff = wk << 10;           // this wave's k-half base

    const float FMAX = expf(fminf(sml[h], MAXLOG)) + 8.0f;

    int qrow[2];
    qrow[0] = q0 + wq * 32 + c;
    qrow[1] = qrow[0] + 16;

    // Q B-fragments for both q-tiles, held the whole sweep.
    bf16x8 qf[2][2];
    #pragma unroll
    for (int qt = 0; qt < 2; ++qt)
        #pragma unroll
        for (int ks = 0; ks < 2; ++ks)
            qf[qt][ks] = *(const bf16x8*)&q[base + (size_t)qrow[qt] * D_ + ks * 32 + quad * 8];

    // cooperative staging geometry (256 threads stage BOTH k-halves):
    //   K half-tile 32x64: thread t -> row kr=t>>3, col kc=(t&7)*8 (b128)
    //   V half-tile 64x32: thread t -> row vr=t>>2, col vc=(t&3)*8 (2x b64)
    const int kr = t >> 3, kc = (t & 7) * 8;
    const int vr = t >> 2, vc = (t & 3) * 8;

    size_t brow[2];
    #pragma unroll
    for (int qt = 0; qt < 2; ++qt)
        brow[qt] = (size_t)qrow[qt] * L_ + koff + 4 * quad;

    float l_acc[2] = {0.f, 0.f};
    f32x4 o[2][4];
    #pragma unroll
    for (int qt = 0; qt < 2; ++qt)
        #pragma unroll
        for (int dt = 0; dt < 4; ++dt) o[qt][dt] = (f32x4){0.f, 0.f, 0.f, 0.f};

    bf16x8 kreg[2], vreg[2];       // [half]
    f32x4  bbA[2][2], bbB[2][2];   // [qt][s]

    // prologue: tiles(0) -> regs -> LDS buf0; tiles(1) -> regs; bias(0),(1)
    #pragma unroll
    for (int hh = 0; hh < 2; ++hh) {
        kreg[hh] = *(const bf16x8*)&k [base  + (size_t)(hh * 1024 + kr) * D_ + kc];
        vreg[hh] = *(const bf16x8*)&vt[vbase + (size_t)vr * L_ + hh * 1024 + vc];
    }
    #pragma unroll
    for (int qt = 0; qt < 2; ++qt)
        #pragma unroll
        for (int s = 0; s < 2; ++s) {
            bbA[qt][s] = *(const f32x4*)&bias[brow[qt] + 16 * s];
            bbB[qt][s] = *(const f32x4*)&bias[brow[qt] + 32 + 16 * s];
        }
    #pragma unroll
    for (int hh = 0; hh < 2; ++hh) {
        *(bf16x8*)&Klds[hh][0][kr][kc] = kreg[hh];
        *(bf16x4*)&Vlds[hh][0][vr][vc]     = __builtin_shufflevector(vreg[hh], vreg[hh], 0,1,2,3);
        *(bf16x4*)&Vlds[hh][0][vr][vc + 4] = __builtin_shufflevector(vreg[hh], vreg[hh], 4,5,6,7);
    }
    #pragma unroll
    for (int hh = 0; hh < 2; ++hh) {
        kreg[hh] = *(const bf16x8*)&k [base  + (size_t)(hh * 1024 + 32 + kr) * D_ + kc];
        vreg[hh] = *(const bf16x8*)&vt[vbase + (size_t)vr * L_ + hh * 1024 + 32 + vc];
    }
    __syncthreads();

// One 32-k tile: write tiles(IT+1) into buf P^1 from regs, prefetch tiles(IT+2)
// + bias(IT+2), compute tile IT from buf P, single barrier.
#define FSTEP(P, BC, IT) do {                                                    \
    if ((IT) + 1 < 32) {                                                         \
        _Pragma("unroll") for (int hh = 0; hh < 2; ++hh) {                       \
            *(bf16x8*)&Klds[hh][(P) ^ 1][kr][kc] = kreg[hh];                     \
            *(bf16x4*)&Vlds[hh][(P) ^ 1][vr][vc]     = __builtin_shufflevector(vreg[hh], vreg[hh], 0,1,2,3); \
            *(bf16x4*)&Vlds[hh][(P) ^ 1][vr][vc + 4] = __builtin_shufflevector(vreg[hh], vreg[hh], 4,5,6,7); \
        }                                                                        \
    }                                                                            \
    f32x4 st[2][2];                                                              \
    _Pragma("unroll") for (int qt = 0; qt < 2; ++qt)                             \
        _Pragma("unroll") for (int s = 0; s < 2; ++s) st[qt][s] = BC[qt][s];     \
    if ((IT) + 2 < 32) {                                                         \
        const int kp = ((IT) + 2) * 32;                                          \
        _Pragma("unroll") for (int hh = 0; hh < 2; ++hh) {                       \
            kreg[hh] = *(const bf16x8*)&k [base  + (size_t)(hh * 1024 + kp + kr) * D_ + kc]; \
            vreg[hh] = *(const bf16x8*)&vt[vbase + (size_t)vr * L_ + hh * 1024 + kp + vc];   \
        }                                                                        \
        _Pragma("unroll") for (int qt = 0; qt < 2; ++qt)                         \
            _Pragma("unroll") for (int s = 0; s < 2; ++s)                        \
                BC[qt][s] = *(const f32x4*)&bias[brow[qt] + kp + 16 * s];        \
    }                                                                            \
    _Pragma("unroll") for (int ks = 0; ks < 2; ++ks)                             \
        _Pragma("unroll") for (int s = 0; s < 2; ++s) {                          \
            const bf16x8 kf = *(const bf16x8*)&Klds[wk][P][s * 16 + c][ks * 32 + quad * 8]; \
            _Pragma("unroll") for (int qt = 0; qt < 2; ++qt)                     \
                st[qt][s] = __builtin_amdgcn_mfma_f32_16x16x32_bf16(kf, qf[qt][ks], st[qt][s], 0, 0, 0); \
        }                                                                        \
    bf16x4 pf[2][2];                                                             \
    _Pragma("unroll") for (int qt = 0; qt < 2; ++qt)                             \
        _Pragma("unroll") for (int s = 0; s < 2; ++s)                            \
            _Pragma("unroll") for (int r = 0; r < 4; ++r) {                      \
                const float pv = __expf(st[qt][s][r] - FMAX);                    \
                l_acc[qt] += pv;                                                 \
                pf[qt][s][r] = (bf16)pv;                                         \
            }                                                                    \
    _Pragma("unroll") for (int s = 0; s < 2; ++s)                                \
        _Pragma("unroll") for (int dt = 0; dt < 4; ++dt) {                       \
            const bf16x4 vfr = *(const bf16x4*)&Vlds[wk][P][dt * 16 + c][16 * s + 4 * quad]; \
            _Pragma("unroll") for (int qt = 0; qt < 2; ++qt)                     \
                o[qt][dt] = mfma16(vfr, pf[qt][s], o[qt][dt]);                   \
        }                                                                        \
    __syncthreads();                                                             \
} while (0)

    for (int it = 0; it < 32; it += 2) {
        FSTEP(0, bbA, it);
        FSTEP(1, bbB, it + 1);
    }
#undef FSTEP

    // per-qt l reduction across quads (quads hold disjoint k rows)
    float lt[2];
    #pragma unroll
    for (int qt = 0; qt < 2; ++qt) {
        float rs = l_acc[qt];
        rs += __shfl_xor(rs, 16);
        rs += __shfl_xor(rs, 32);
        lt[qt] = rs;
    }

    // merge the two k-halves through LDS (v6-proven epilogue)
    if (wk == 1) {
        #pragma unroll
        for (int qt = 0; qt < 2; ++qt)
            #pragma unroll
            for (int dt = 0; dt < 4; ++dt)
                *(f32x4*)&OfT[wq][qt][dt][lane][0] = o[qt][dt];
        if (quad == 0) {
            lfs[wq][0][c] = lt[0];
            lfs[wq][1][c] = lt[1];
        }
    }
    __syncthreads();
    if (wk == 0) {
        #pragma unroll
        for (int qt = 0; qt < 2; ++qt) {
            const float linv = 1.0f / (lt[qt] + lfs[wq][qt][c]);
            const size_t obase = ((size_t)(b * L_ + qrow[qt])) * C_ + h * 64;
            #pragma unroll
            for (int dt = 0; dt < 4; ++dt) {
                const f32x4 m = *(const f32x4*)&OfT[wq][qt][dt][lane][0];
                bf16x4 hv, lv;
                #pragma unroll
                for (int r = 0; r < 4; ++r) {
                    const float v = (o[qt][dt][r] + m[r]) * linv;
                    hv[r] = (bf16)v;
                    lv[r] = (bf16)(v - (float)hv[r]);
                }
                *(bf16x4*)&aoh[obase + dt * 16 + 4 * quad] = hv;
                *(bf16x4*)&aol[obase + dt * 16 + 4 * quad] = lv;
            }
        }
    }
}

// ---------------------------------------------------------------------------
// Kernel 3: projection GEMM (unchanged R7).
// ---------------------------------------------------------------------------
__global__ __launch_bounds__(256) void proj_mfma(
    const bf16* __restrict__ Ahg, const bf16* __restrict__ Alg,
    const bf16* __restrict__ Whg, const bf16* __restrict__ Wlg,
    const float* __restrict__ bias, float* __restrict__ outp)
{
    __shared__ __align__(16) bf16 Ah[64][64];
    __shared__ __align__(16) bf16 Al[64][64];
    __shared__ __align__(16) bf16 Bh[64][64];
    __shared__ __align__(16) bf16 Bl[64][64];

    const int t    = threadIdx.x;
    const int w    = t >> 6;
    const int lane = t & 63;
    const int quad = lane >> 4;
    const int c    = lane & 15;
    const int m0   = blockIdx.x * 64;
    const int n0   = blockIdx.y * 64;

    const int sr = t >> 3;
    const int sc = t & 7;
    const int sx = sc ^ (sr & 7);

    f32x4 acc[4];
    #pragma unroll
    for (int nt = 0; nt < 4; ++nt) acc[nt] = (f32x4){0.f,0.f,0.f,0.f};

    for (int kt = 0; kt < C_; kt += 64) {
        __syncthreads();
        #pragma unroll
        for (int p = 0; p < 2; ++p) {
            const size_t ga = (size_t)(m0 + 32 * p + sr) * C_ + kt + 8 * sx;
            const size_t gb = (size_t)(n0 + 32 * p + sr) * C_ + kt + 8 * sx;
            const int    lo = (p * 256 + t) * 16;
            stage16(&Ahg[ga], (char*)&Ah[0][0] + lo);
            stage16(&Alg[ga], (char*)&Al[0][0] + lo);
            stage16(&Whg[gb], (char*)&Bh[0][0] + lo);
            stage16(&Wlg[gb], (char*)&Bl[0][0] + lo);
        }
        __syncthreads();

        #pragma unroll
        for (int ks = 0; ks < 2; ++ks) {
            const int rchunk = ((4 * ks + quad) ^ (c & 7)) * 16;
            const bf16x8 ah = *(const bf16x8*)((const char*)&Ah[0][0]
                              + (size_t)(w * 16 + c) * 128 + rchunk);
            const bf16x8 al = *(const bf16x8*)((const char*)&Al[0][0]
                              + (size_t)(w * 16 + c) * 128 + rchunk);
            #pragma unroll
            for (int nt = 0; nt < 4; ++nt) {
                const bf16x8 bh = *(const bf16x8*)((const char*)&Bh[0][0]
                                  + (size_t)(nt * 16 + c) * 128 + rchunk);
                const bf16x8 bl = *(const bf16x8*)((const char*)&Bl[0][0]
                                  + (size_t)(nt * 16 + c) * 128 + rchunk);
                acc[nt] = __builtin_amdgcn_mfma_f32_16x16x32_bf16(ah, bh, acc[nt], 0, 0, 0);
                acc[nt] = __builtin_amdgcn_mfma_f32_16x16x32_bf16(ah, bl, acc[nt], 0, 0, 0);
                acc[nt] = __builtin_amdgcn_mfma_f32_16x16x32_bf16(al, bh, acc[nt], 0, 0, 0);
            }
        }
    }

    #pragma unroll
    for (int nt = 0; nt < 4; ++nt) {
        const int col = n0 + nt * 16 + c;
        const float bb = bias[col];
        #pragma unroll
        for (int reg = 0; reg < 4; ++reg) {
            const int row = m0 + w * 16 + quad * 4 + reg;
            outp[(size_t)row * C_ + col] = acc[nt][reg] + bb;
        }
    }
}

// ---------------------------------------------------------------------------
extern "C" void kernel_launch(void* const* d_in, const int* in_sizes, int n_in,
                              void* d_out, int out_size, void* d_ws, size_t ws_size,
                              hipStream_t stream)
{
    const float* x         = (const float*)d_in[0];
    const float* attn_bias = (const float*)d_in[1];
    const float* W_qkv     = (const float*)d_in[2];
    const float* b_qkv     = (const float*)d_in[3];
    const float* sml       = (const float*)d_in[4];
    const float* W_proj    = (const float*)d_in[5];
    const float* b_proj    = (const float*)d_in[6];
    float* out = (float*)d_out;

    // ws layout (bf16 elements): qb,kb,vtb | aoh,aol | Wh,Wl | xb | wqb
    bf16* qb  = (bf16*)d_ws;
    bf16* kb  = qb  + SZ_;
    bf16* vtb = kb  + SZ_;
    bf16* aoh = vtb + SZ_;
    bf16* aol = aoh + MC_;
    bf16* Wh  = aol + MC_;
    bf16* Wl  = Wh  + WP_;
    bf16* xb  = Wl  + WP_;
    bf16* wqb = xb  + MC_;

    // 0) fused prep
    prep<<<2048, 256, 0, stream>>>(
        (const float4*)x, (const float4*)W_qkv, (const float4*)W_proj,
        xb, wqb, Wh, Wl);

    // 1) QKV GEMM
    qkv_mfma<<<dim3(M_ / 128, (3 * C_) / 64), 256, 0, stream>>>(
        xb, wqb, b_qkv, sml, qb, kb, vtb);

    // 2) flash attention v11: 32q/wave x k-half waves, BK=32 dbuf, LDS merge
    flash_mfma<<<dim3(L_ / 64, B_ * H_), 256, 0, stream>>>(
        qb, kb, vtb, attn_bias, sml, aoh, aol);

    // 3) projection GEMM
    proj_mfma<<<dim3(M_ / 64, C_ / 64), 256, 0, stream>>>(
        aoh, aol, Wh, Wl, b_proj, out);
}

// Round 10
// 206.935 us; speedup vs baseline: 1.1400x; 1.1400x over previous
//
#include <hip/hip_runtime.h>
#include <math.h>

#define B_ 2
#define L_ 2048
#define C_ 768
#define H_ 12
#define D_ 64
#define M_ (B_ * L_)          // 4096
#define MAXLOG 4.605170185988091f   // log(100)

typedef __bf16 bf16;
typedef __bf16 bf16x4 __attribute__((ext_vector_type(4)));
typedef __bf16 bf16x8 __attribute__((ext_vector_type(8)));
typedef float  f32x4  __attribute__((ext_vector_type(4)));
typedef short  s16x4  __attribute__((ext_vector_type(4)));

// workspace element counts
#define SZ_  ((size_t)B_ * H_ * L_ * D_)   // 3,145,728 (q,k,vt each)
#define MC_  ((size_t)M_ * C_)             // 3,145,728 (x / ao)
#define WQ_  ((size_t)3 * C_ * C_)         // 1,769,472 (W_qkv)
#define WP_  ((size_t)C_ * C_)             //   589,824 (W_proj)

// K=16 bf16 MFMA. S^T accumulator layout (row=4*quad+reg, col=lane&15) equals
// this op's B-fragment layout, so P^T feeds PV directly from registers.
static __device__ __forceinline__ f32x4 mfma16(bf16x4 a, bf16x4 b, f32x4 c) {
#if __has_builtin(__builtin_amdgcn_mfma_f32_16x16x16_bf16)
    return __builtin_amdgcn_mfma_f32_16x16x16_bf16(a, b, c, 0, 0, 0);
#elif __has_builtin(__builtin_amdgcn_mfma_f32_16x16x16bf16_1k)
    return __builtin_amdgcn_mfma_f32_16x16x16bf16_1k(*(s16x4*)&a, *(s16x4*)&b, c, 0, 0, 0);
#else
    f32x4 d;
    asm("v_mfma_f32_16x16x16_bf16 %0, %1, %2, %3" : "=v"(d) : "v"(a), "v"(b), "v"(c));
    return d;
#endif
}

// 16B async global->LDS stage (GEMMs only; LDS dest linear in lane).
static __device__ __forceinline__ void stage16(const bf16* gsrc, void* ldst) {
#if __has_builtin(__builtin_amdgcn_global_load_lds)
    __builtin_amdgcn_global_load_lds(
        (const __attribute__((address_space(1))) unsigned int*)gsrc,
        (__attribute__((address_space(3))) unsigned int*)ldst, 16, 0, 0);
#else
    *(bf16x8*)ldst = *(const bf16x8*)gsrc;
#endif
}

// ---------------------------------------------------------------------------
// Kernel 0: fused prep (unchanged R7).
// ---------------------------------------------------------------------------
__global__ __launch_bounds__(256) void prep(
    const float4* __restrict__ x, const float4* __restrict__ Wq,
    const float4* __restrict__ Wp,
    bf16* __restrict__ xb, bf16* __restrict__ wqb,
    bf16* __restrict__ Wh, bf16* __restrict__ Wl)
{
    const int X4 = (int)(MC_ / 4);
    const int W4 = (int)(WQ_ / 4);
    const int S4 = (int)(WP_ / 4);
    const int total = X4 + W4 + S4;

    const int i0 = blockIdx.x * 256 + threadIdx.x;
    const int stride = gridDim.x * 256;
    for (int i = i0; i < total; i += stride) {
        if (i < X4) {
            const float4 v = x[i];
            bf16x4 o; o[0]=(bf16)v.x; o[1]=(bf16)v.y; o[2]=(bf16)v.z; o[3]=(bf16)v.w;
            *(bf16x4*)&xb[(size_t)i * 4] = o;
        } else if (i < X4 + W4) {
            const int j = i - X4;
            const float4 v = Wq[j];
            bf16x4 o; o[0]=(bf16)v.x; o[1]=(bf16)v.y; o[2]=(bf16)v.z; o[3]=(bf16)v.w;
            *(bf16x4*)&wqb[(size_t)j * 4] = o;
        } else {
            const int j = i - X4 - W4;
            const float4 v = Wp[j];
            bf16x4 h, l;
            h[0]=(bf16)v.x; l[0]=(bf16)(v.x-(float)h[0]);
            h[1]=(bf16)v.y; l[1]=(bf16)(v.y-(float)h[1]);
            h[2]=(bf16)v.z; l[2]=(bf16)(v.z-(float)h[2]);
            h[3]=(bf16)v.w; l[3]=(bf16)(v.w-(float)h[3]);
            *(bf16x4*)&Wh[(size_t)j * 4] = h;
            *(bf16x4*)&Wl[(size_t)j * 4] = l;
        }
    }
}

// ---------------------------------------------------------------------------
// Kernel 1: QKV GEMM (unchanged R7: DMA staging, linear LDS + XOR swizzle).
// ---------------------------------------------------------------------------
__global__ __launch_bounds__(256) void qkv_mfma(
    const bf16* __restrict__ A, const bf16* __restrict__ W,
    const float* __restrict__ bias, const float* __restrict__ sml,
    bf16* __restrict__ qb, bf16* __restrict__ kb, bf16* __restrict__ vtb)
{
    __shared__ __align__(16) bf16 As[128][64];
    __shared__ __align__(16) bf16 Bs[64][64];

    const int t    = threadIdx.x;
    const int w    = t >> 6;
    const int lane = t & 63;
    const int quad = lane >> 4;
    const int c    = lane & 15;
    const int m0   = blockIdx.x * 128;
    const int n0   = blockIdx.y * 64;

    const int sr = t >> 3;
    const int sc = t & 7;
    const int sx = sc ^ (sr & 7);

    f32x4 acc[2][4];
    #pragma unroll
    for (int mt = 0; mt < 2; ++mt)
        #pragma unroll
        for (int nt = 0; nt < 4; ++nt) acc[mt][nt] = (f32x4){0.f,0.f,0.f,0.f};

    for (int kt = 0; kt < C_; kt += 64) {
        __syncthreads();
        #pragma unroll
        for (int p = 0; p < 4; ++p)
            stage16(&A[(size_t)(m0 + 32 * p + sr) * C_ + kt + 8 * sx],
                    (char*)&As[0][0] + (p * 256 + t) * 16);
        #pragma unroll
        for (int p = 0; p < 2; ++p)
            stage16(&W[(size_t)(n0 + 32 * p + sr) * C_ + kt + 8 * sx],
                    (char*)&Bs[0][0] + (p * 256 + t) * 16);
        __syncthreads();

        #pragma unroll
        for (int ks = 0; ks < 2; ++ks) {
            const int rchunk = ((4 * ks + quad) ^ (c & 7)) * 16;
            #pragma unroll
            for (int mt = 0; mt < 2; ++mt) {
                const bf16x8 a = *(const bf16x8*)((const char*)&As[0][0]
                                 + (size_t)(w * 32 + mt * 16 + c) * 128 + rchunk);
                #pragma unroll
                for (int nt = 0; nt < 4; ++nt) {
                    const bf16x8 b = *(const bf16x8*)((const char*)&Bs[0][0]
                                     + (size_t)(nt * 16 + c) * 128 + rchunk);
                    acc[mt][nt] = __builtin_amdgcn_mfma_f32_16x16x32_bf16(a, b, acc[mt][nt], 0, 0, 0);
                }
            }
        }
    }

    const int three = blockIdx.y / H_;
    const int h     = blockIdx.y % H_;
    const int bidx  = m0 >> 11;
    const int l0    = (m0 & (L_ - 1)) + w * 32;

    if (three < 2) {
        bf16* dst = (three == 0) ? qb : kb;
        const float scale = (three == 0) ? expf(fminf(sml[h], MAXLOG)) : 1.0f;
        #pragma unroll
        for (int mt = 0; mt < 2; ++mt) {
            float val[4][4];
            float ss[4] = {0.f, 0.f, 0.f, 0.f};
            #pragma unroll
            for (int nt = 0; nt < 4; ++nt) {
                const float bb = bias[n0 + nt * 16 + c];
                #pragma unroll
                for (int reg = 0; reg < 4; ++reg) {
                    const float v = acc[mt][nt][reg] + bb;
                    val[nt][reg] = v;
                    ss[reg] += v * v;
                }
            }
            #pragma unroll
            for (int reg = 0; reg < 4; ++reg) {
                float s = ss[reg];
                #pragma unroll
                for (int off = 1; off < 16; off <<= 1) s += __shfl_xor(s, off, 16);
                const float inv = scale / fmaxf(sqrtf(s), 1e-12f);
                const int l = l0 + mt * 16 + quad * 4 + reg;
                #pragma unroll
                for (int nt = 0; nt < 4; ++nt)
                    dst[((size_t)(bidx * H_ + h) * L_ + l) * D_ + nt * 16 + c] =
                        (bf16)(val[nt][reg] * inv);
            }
        }
    } else {
        #pragma unroll
        for (int mt = 0; mt < 2; ++mt)
            #pragma unroll
            for (int nt = 0; nt < 4; ++nt) {
                const int d = nt * 16 + c;
                const float bb = bias[n0 + d];
                const int l = l0 + mt * 16 + quad * 4;
                bf16x4 o;
                #pragma unroll
                for (int reg = 0; reg < 4; ++reg) o[reg] = (bf16)(acc[mt][nt][reg] + bb);
                *(bf16x4*)&vtb[((size_t)(bidx * H_ + h) * D_ + d) * L_ + l] = o;
            }
    }
}

// ---------------------------------------------------------------------------
// Kernel 2: flash attention v12 — 128-thread blocks (2 waves x 16q = BQ=32),
//   BK=32, grid 1536 (6 blocks/CU x 2 waves = 12 waves/CU, same TLP as v7).
//   Per-wave math identical to v7; per-step register state halved (st[2],
//   bias dbuf 16 VGPR) -> ~70 VGPR, far from the 85-VGPR spill cliff that
//   killed v10/v11. V LDS pitch 36: b64 PV reads land on 16 distinct even
//   word offsets (18c mod 32) -> conflict-free. 2-wave barriers, 6 indep
//   blocks/CU for phase drift.
// ---------------------------------------------------------------------------
__global__ __launch_bounds__(128, 3) void flash_mfma(
    const bf16* __restrict__ q, const bf16* __restrict__ k,
    const bf16* __restrict__ vt, const float* __restrict__ bias,
    const float* __restrict__ sml,
    bf16* __restrict__ aoh, bf16* __restrict__ aol)
{
    __shared__ __align__(16) bf16 Klds[2][32][72];   // [buf][krow][d]  9 KB
    __shared__ __align__(16) bf16 Vlds[2][64][36];   // [buf][drow][k]  9 KB

    const int t    = threadIdx.x;
    const int w    = t >> 6;        // 0..1
    const int lane = t & 63;
    const int quad = lane >> 4;
    const int c    = lane & 15;
    const int q0   = blockIdx.x * 32;
    const int bh   = blockIdx.y;
    const int h    = bh % H_;
    const int b    = bh / H_;
    const size_t base  = (size_t)bh * L_ * D_;
    const size_t vbase = (size_t)bh * D_ * L_;
    const int qrow = q0 + w * 16 + c;      // this lane's q index (column of S^T)

    const float FMAX = expf(fminf(sml[h], MAXLOG)) + 8.0f;

    // Q B-fragments straight from global, held for the whole sweep.
    bf16x8 qf[2];
    qf[0] = *(const bf16x8*)&q[base + (size_t)qrow * D_ + quad * 8];
    qf[1] = *(const bf16x8*)&q[base + (size_t)qrow * D_ + 32 + quad * 8];

    // staging geometry (128 threads, BK=32):
    //   K tile 32x64: 2 sweeps b128: row 16j + (t>>3), col (t&7)*8
    //   V tile 64x32: 2 sweeps b128: row 32j + (t>>2), chunk (t&3)*8
    const int kr = t >> 3, kc = (t & 7) * 8;
    const int vr = t >> 2, vc = (t & 3) * 8;

    const size_t brow = (size_t)qrow * L_ + 4 * quad;

    float l_acc = 0.f;
    f32x4 o[4];
    #pragma unroll
    for (int dt = 0; dt < 4; ++dt) o[dt] = (f32x4){0.f, 0.f, 0.f, 0.f};

    bf16x8 kreg[2], vreg[2];
    f32x4  bbA[2], bbB[2];

    // prologue: tile 0 -> regs -> LDS buf0; tile 1 -> regs; bias 0/1 -> regs
    #pragma unroll
    for (int j = 0; j < 2; ++j) {
        kreg[j] = *(const bf16x8*)&k [base  + (size_t)(16 * j + kr) * D_ + kc];
        vreg[j] = *(const bf16x8*)&vt[vbase + (size_t)(32 * j + vr) * L_ + vc];
    }
    #pragma unroll
    for (int s = 0; s < 2; ++s) {
        bbA[s] = *(const f32x4*)&bias[brow + 16 * s];
        bbB[s] = *(const f32x4*)&bias[brow + 32 + 16 * s];
    }
    #pragma unroll
    for (int j = 0; j < 2; ++j) {
        *(bf16x8*)&Klds[0][16 * j + kr][kc] = kreg[j];
        *(bf16x8*)&Vlds[0][32 * j + vr][vc] = vreg[j];
    }
    #pragma unroll
    for (int j = 0; j < 2; ++j) {
        kreg[j] = *(const bf16x8*)&k [base  + (size_t)(32 + 16 * j + kr) * D_ + kc];
        vreg[j] = *(const bf16x8*)&vt[vbase + (size_t)(32 * j + vr) * L_ + 32 + vc];
    }
    __syncthreads();

// One 32-k tile: stage tile IT+1 from regs, prefetch tile IT+2 + bias IT+2,
// compute tile IT (4 QK mfma + 8 exp + 8 PV mfma), single barrier.
#define FSTEP(P, BC, IT) do {                                                    \
    if ((IT) + 1 < 64) {                                                         \
        _Pragma("unroll") for (int j = 0; j < 2; ++j) {                          \
            *(bf16x8*)&Klds[(P) ^ 1][16 * j + kr][kc] = kreg[j];                 \
            *(bf16x8*)&Vlds[(P) ^ 1][32 * j + vr][vc] = vreg[j];                 \
        }                                                                        \
    }                                                                            \
    f32x4 st[2];                                                                 \
    _Pragma("unroll") for (int s = 0; s < 2; ++s) st[s] = BC[s];                 \
    if ((IT) + 2 < 64) {                                                         \
        const int kp = ((IT) + 2) * 32;                                          \
        _Pragma("unroll") for (int j = 0; j < 2; ++j) {                          \
            kreg[j] = *(const bf16x8*)&k [base  + (size_t)(kp + 16 * j + kr) * D_ + kc]; \
            vreg[j] = *(const bf16x8*)&vt[vbase + (size_t)(32 * j + vr) * L_ + kp + vc]; \
        }                                                                        \
        _Pragma("unroll") for (int s = 0; s < 2; ++s)                            \
            BC[s] = *(const f32x4*)&bias[brow + kp + 16 * s];                    \
    }                                                                            \
    _Pragma("unroll") for (int ks = 0; ks < 2; ++ks)                             \
        _Pragma("unroll") for (int s = 0; s < 2; ++s) {                          \
            const bf16x8 kf = *(const bf16x8*)&Klds[P][s * 16 + c][ks * 32 + quad * 8]; \
            st[s] = __builtin_amdgcn_mfma_f32_16x16x32_bf16(kf, qf[ks], st[s], 0, 0, 0); \
        }                                                                        \
    bf16x4 pf[2];                                                                \
    _Pragma("unroll") for (int s = 0; s < 2; ++s)                                \
        _Pragma("unroll") for (int r = 0; r < 4; ++r) {                          \
            const float pv = __expf(st[s][r] - FMAX);                            \
            l_acc += pv;                                                         \
            pf[s][r] = (bf16)pv;                                                 \
        }                                                                        \
    _Pragma("unroll") for (int s = 0; s < 2; ++s)                                \
        _Pragma("unroll") for (int dt = 0; dt < 4; ++dt) {                       \
            const bf16x4 vfr = *(const bf16x4*)&Vlds[P][dt * 16 + c][16 * s + 4 * quad]; \
            o[dt] = mfma16(vfr, pf[s], o[dt]);                                   \
        }                                                                        \
    __syncthreads();                                                             \
} while (0)

    for (int it = 0; it < 64; it += 2) {
        FSTEP(0, bbA, it);
        FSTEP(1, bbB, it + 1);
    }
#undef FSTEP

    // l: lane holds k-rows 4*quad+0..3 of every tile; reduce across quads.
    float rs = l_acc;
    rs += __shfl_xor(rs, 16);
    rs += __shfl_xor(rs, 32);
    const float linv = 1.0f / rs;

    const size_t obase = ((size_t)(b * L_ + qrow)) * C_ + h * 64;
    #pragma unroll
    for (int dt = 0; dt < 4; ++dt) {
        bf16x4 hv, lv;
        #pragma unroll
        for (int r = 0; r < 4; ++r) {
            const float v = o[dt][r] * linv;
            hv[r] = (bf16)v;
            lv[r] = (bf16)(v - (float)hv[r]);
        }
        *(bf16x4*)&aoh[obase + dt * 16 + 4 * quad] = hv;
        *(bf16x4*)&aol[obase + dt * 16 + 4 * quad] = lv;
    }
}

// ---------------------------------------------------------------------------
// Kernel 3: projection GEMM (unchanged R7).
// ---------------------------------------------------------------------------
__global__ __launch_bounds__(256) void proj_mfma(
    const bf16* __restrict__ Ahg, const bf16* __restrict__ Alg,
    const bf16* __restrict__ Whg, const bf16* __restrict__ Wlg,
    const float* __restrict__ bias, float* __restrict__ outp)
{
    __shared__ __align__(16) bf16 Ah[64][64];
    __shared__ __align__(16) bf16 Al[64][64];
    __shared__ __align__(16) bf16 Bh[64][64];
    __shared__ __align__(16) bf16 Bl[64][64];

    const int t    = threadIdx.x;
    const int w    = t >> 6;
    const int lane = t & 63;
    const int quad = lane >> 4;
    const int c    = lane & 15;
    const int m0   = blockIdx.x * 64;
    const int n0   = blockIdx.y * 64;

    const int sr = t >> 3;
    const int sc = t & 7;
    const int sx = sc ^ (sr & 7);

    f32x4 acc[4];
    #pragma unroll
    for (int nt = 0; nt < 4; ++nt) acc[nt] = (f32x4){0.f,0.f,0.f,0.f};

    for (int kt = 0; kt < C_; kt += 64) {
        __syncthreads();
        #pragma unroll
        for (int p = 0; p < 2; ++p) {
            const size_t ga = (size_t)(m0 + 32 * p + sr) * C_ + kt + 8 * sx;
            const size_t gb = (size_t)(n0 + 32 * p + sr) * C_ + kt + 8 * sx;
            const int    lo = (p * 256 + t) * 16;
            stage16(&Ahg[ga], (char*)&Ah[0][0] + lo);
            stage16(&Alg[ga], (char*)&Al[0][0] + lo);
            stage16(&Whg[gb], (char*)&Bh[0][0] + lo);
            stage16(&Wlg[gb], (char*)&Bl[0][0] + lo);
        }
        __syncthreads();

        #pragma unroll
        for (int ks = 0; ks < 2; ++ks) {
            const int rchunk = ((4 * ks + quad) ^ (c & 7)) * 16;
            const bf16x8 ah = *(const bf16x8*)((const char*)&Ah[0][0]
                              + (size_t)(w * 16 + c) * 128 + rchunk);
            const bf16x8 al = *(const bf16x8*)((const char*)&Al[0][0]
                              + (size_t)(w * 16 + c) * 128 + rchunk);
            #pragma unroll
            for (int nt = 0; nt < 4; ++nt) {
                const bf16x8 bh = *(const bf16x8*)((const char*)&Bh[0][0]
                                  + (size_t)(nt * 16 + c) * 128 + rchunk);
                const bf16x8 bl = *(const bf16x8*)((const char*)&Bl[0][0]
                                  + (size_t)(nt * 16 + c) * 128 + rchunk);
                acc[nt] = __builtin_amdgcn_mfma_f32_16x16x32_bf16(ah, bh, acc[nt], 0, 0, 0);
                acc[nt] = __builtin_amdgcn_mfma_f32_16x16x32_bf16(ah, bl, acc[nt], 0, 0, 0);
                acc[nt] = __builtin_amdgcn_mfma_f32_16x16x32_bf16(al, bh, acc[nt], 0, 0, 0);
            }
        }
    }

    #pragma unroll
    for (int nt = 0; nt < 4; ++nt) {
        const int col = n0 + nt * 16 + c;
        const float bb = bias[col];
        #pragma unroll
        for (int reg = 0; reg < 4; ++reg) {
            const int row = m0 + w * 16 + quad * 4 + reg;
            outp[(size_t)row * C_ + col] = acc[nt][reg] + bb;
        }
    }
}

// ---------------------------------------------------------------------------
extern "C" void kernel_launch(void* const* d_in, const int* in_sizes, int n_in,
                              void* d_out, int out_size, void* d_ws, size_t ws_size,
                              hipStream_t stream)
{
    const float* x         = (const float*)d_in[0];
    const float* attn_bias = (const float*)d_in[1];
    const float* W_qkv     = (const float*)d_in[2];
    const float* b_qkv     = (const float*)d_in[3];
    const float* sml       = (const float*)d_in[4];
    const float* W_proj    = (const float*)d_in[5];
    const float* b_proj    = (const float*)d_in[6];
    float* out = (float*)d_out;

    // ws layout (bf16 elements): qb,kb,vtb | aoh,aol | Wh,Wl | xb | wqb
    bf16* qb  = (bf16*)d_ws;
    bf16* kb  = qb  + SZ_;
    bf16* vtb = kb  + SZ_;
    bf16* aoh = vtb + SZ_;
    bf16* aol = aoh + MC_;
    bf16* Wh  = aol + MC_;
    bf16* Wl  = Wh  + WP_;
    bf16* xb  = Wl  + WP_;
    bf16* wqb = xb  + MC_;

    // 0) fused prep
    prep<<<2048, 256, 0, stream>>>(
        (const float4*)x, (const float4*)W_qkv, (const float4*)W_proj,
        xb, wqb, Wh, Wl);

    // 1) QKV GEMM
    qkv_mfma<<<dim3(M_ / 128, (3 * C_) / 64), 256, 0, stream>>>(
        xb, wqb, b_qkv, sml, qb, kb, vtb);

    // 2) flash attention v12: 128-thr blocks, BQ=32, BK=32, grid 1536
    flash_mfma<<<dim3(L_ / 32, B_ * H_), 128, 0, stream>>>(
        qb, kb, vtb, attn_bias, sml, aoh, aol);

    // 3) projection GEMM
    proj_mfma<<<dim3(M_ / 64, C_ / 64), 256, 0, stream>>>(
        aoh, aol, Wh, Wl, b_proj, out);
}

// Round 11
// 203.423 us; speedup vs baseline: 1.1597x; 1.0173x over previous
//
#include <hip/hip_runtime.h>
#include <math.h>

#define B_ 2
#define L_ 2048
#define C_ 768
#define H_ 12
#define D_ 64
#define M_ (B_ * L_)          // 4096
#define MAXLOG 4.605170185988091f   // log(100)

typedef __bf16 bf16;
typedef __bf16 bf16x4 __attribute__((ext_vector_type(4)));
typedef __bf16 bf16x8 __attribute__((ext_vector_type(8)));
typedef float  f32x4  __attribute__((ext_vector_type(4)));
typedef short  s16x4  __attribute__((ext_vector_type(4)));

// workspace element counts
#define SZ_  ((size_t)B_ * H_ * L_ * D_)   // 3,145,728 (q,k,vt each)
#define MC_  ((size_t)M_ * C_)             // 3,145,728 (x / ao)
#define WQ_  ((size_t)3 * C_ * C_)         // 1,769,472 (W_qkv)
#define WP_  ((size_t)C_ * C_)             //   589,824 (W_proj)

// K=16 bf16 MFMA. S^T accumulator layout (row=4*quad+reg, col=lane&15) equals
// this op's B-fragment layout, so P^T feeds PV directly from registers.
static __device__ __forceinline__ f32x4 mfma16(bf16x4 a, bf16x4 b, f32x4 c) {
#if __has_builtin(__builtin_amdgcn_mfma_f32_16x16x16_bf16)
    return __builtin_amdgcn_mfma_f32_16x16x16_bf16(a, b, c, 0, 0, 0);
#elif __has_builtin(__builtin_amdgcn_mfma_f32_16x16x16bf16_1k)
    return __builtin_amdgcn_mfma_f32_16x16x16bf16_1k(*(s16x4*)&a, *(s16x4*)&b, c, 0, 0, 0);
#else
    f32x4 d;
    asm("v_mfma_f32_16x16x16_bf16 %0, %1, %2, %3" : "=v"(d) : "v"(a), "v"(b), "v"(c));
    return d;
#endif
}

// 16B async global->LDS stage (GEMMs only; LDS dest linear in lane).
static __device__ __forceinline__ void stage16(const bf16* gsrc, void* ldst) {
#if __has_builtin(__builtin_amdgcn_global_load_lds)
    __builtin_amdgcn_global_load_lds(
        (const __attribute__((address_space(1))) unsigned int*)gsrc,
        (__attribute__((address_space(3))) unsigned int*)ldst, 16, 0, 0);
#else
    *(bf16x8*)ldst = *(const bf16x8*)gsrc;
#endif
}

// ---------------------------------------------------------------------------
// Kernel 0: fused prep (unchanged R7).
// ---------------------------------------------------------------------------
__global__ __launch_bounds__(256) void prep(
    const float4* __restrict__ x, const float4* __restrict__ Wq,
    const float4* __restrict__ Wp,
    bf16* __restrict__ xb, bf16* __restrict__ wqb,
    bf16* __restrict__ Wh, bf16* __restrict__ Wl)
{
    const int X4 = (int)(MC_ / 4);
    const int W4 = (int)(WQ_ / 4);
    const int S4 = (int)(WP_ / 4);
    const int total = X4 + W4 + S4;

    const int i0 = blockIdx.x * 256 + threadIdx.x;
    const int stride = gridDim.x * 256;
    for (int i = i0; i < total; i += stride) {
        if (i < X4) {
            const float4 v = x[i];
            bf16x4 o; o[0]=(bf16)v.x; o[1]=(bf16)v.y; o[2]=(bf16)v.z; o[3]=(bf16)v.w;
            *(bf16x4*)&xb[(size_t)i * 4] = o;
        } else if (i < X4 + W4) {
            const int j = i - X4;
            const float4 v = Wq[j];
            bf16x4 o; o[0]=(bf16)v.x; o[1]=(bf16)v.y; o[2]=(bf16)v.z; o[3]=(bf16)v.w;
            *(bf16x4*)&wqb[(size_t)j * 4] = o;
        } else {
            const int j = i - X4 - W4;
            const float4 v = Wp[j];
            bf16x4 h, l;
            h[0]=(bf16)v.x; l[0]=(bf16)(v.x-(float)h[0]);
            h[1]=(bf16)v.y; l[1]=(bf16)(v.y-(float)h[1]);
            h[2]=(bf16)v.z; l[2]=(bf16)(v.z-(float)h[2]);
            h[3]=(bf16)v.w; l[3]=(bf16)(v.w-(float)h[3]);
            *(bf16x4*)&Wh[(size_t)j * 4] = h;
            *(bf16x4*)&Wl[(size_t)j * 4] = l;
        }
    }
}

// ---------------------------------------------------------------------------
// Kernel 1: QKV GEMM (unchanged R7: DMA staging, linear LDS + XOR swizzle).
// ---------------------------------------------------------------------------
__global__ __launch_bounds__(256) void qkv_mfma(
    const bf16* __restrict__ A, const bf16* __restrict__ W,
    const float* __restrict__ bias, const float* __restrict__ sml,
    bf16* __restrict__ qb, bf16* __restrict__ kb, bf16* __restrict__ vtb)
{
    __shared__ __align__(16) bf16 As[128][64];
    __shared__ __align__(16) bf16 Bs[64][64];

    const int t    = threadIdx.x;
    const int w    = t >> 6;
    const int lane = t & 63;
    const int quad = lane >> 4;
    const int c    = lane & 15;
    const int m0   = blockIdx.x * 128;
    const int n0   = blockIdx.y * 64;

    const int sr = t >> 3;
    const int sc = t & 7;
    const int sx = sc ^ (sr & 7);

    f32x4 acc[2][4];
    #pragma unroll
    for (int mt = 0; mt < 2; ++mt)
        #pragma unroll
        for (int nt = 0; nt < 4; ++nt) acc[mt][nt] = (f32x4){0.f,0.f,0.f,0.f};

    for (int kt = 0; kt < C_; kt += 64) {
        __syncthreads();
        #pragma unroll
        for (int p = 0; p < 4; ++p)
            stage16(&A[(size_t)(m0 + 32 * p + sr) * C_ + kt + 8 * sx],
                    (char*)&As[0][0] + (p * 256 + t) * 16);
        #pragma unroll
        for (int p = 0; p < 2; ++p)
            stage16(&W[(size_t)(n0 + 32 * p + sr) * C_ + kt + 8 * sx],
                    (char*)&Bs[0][0] + (p * 256 + t) * 16);
        __syncthreads();

        #pragma unroll
        for (int ks = 0; ks < 2; ++ks) {
            const int rchunk = ((4 * ks + quad) ^ (c & 7)) * 16;
            #pragma unroll
            for (int mt = 0; mt < 2; ++mt) {
                const bf16x8 a = *(const bf16x8*)((const char*)&As[0][0]
                                 + (size_t)(w * 32 + mt * 16 + c) * 128 + rchunk);
                #pragma unroll
                for (int nt = 0; nt < 4; ++nt) {
                    const bf16x8 b = *(const bf16x8*)((const char*)&Bs[0][0]
                                     + (size_t)(nt * 16 + c) * 128 + rchunk);
                    acc[mt][nt] = __builtin_amdgcn_mfma_f32_16x16x32_bf16(a, b, acc[mt][nt], 0, 0, 0);
                }
            }
        }
    }

    const int three = blockIdx.y / H_;
    const int h     = blockIdx.y % H_;
    const int bidx  = m0 >> 11;
    const int l0    = (m0 & (L_ - 1)) + w * 32;

    if (three < 2) {
        bf16* dst = (three == 0) ? qb : kb;
        const float scale = (three == 0) ? expf(fminf(sml[h], MAXLOG)) : 1.0f;
        #pragma unroll
        for (int mt = 0; mt < 2; ++mt) {
            float val[4][4];
            float ss[4] = {0.f, 0.f, 0.f, 0.f};
            #pragma unroll
            for (int nt = 0; nt < 4; ++nt) {
                const float bb = bias[n0 + nt * 16 + c];
                #pragma unroll
                for (int reg = 0; reg < 4; ++reg) {
                    const float v = acc[mt][nt][reg] + bb;
                    val[nt][reg] = v;
                    ss[reg] += v * v;
                }
            }
            #pragma unroll
            for (int reg = 0; reg < 4; ++reg) {
                float s = ss[reg];
                #pragma unroll
                for (int off = 1; off < 16; off <<= 1) s += __shfl_xor(s, off, 16);
                const float inv = scale / fmaxf(sqrtf(s), 1e-12f);
                const int l = l0 + mt * 16 + quad * 4 + reg;
                #pragma unroll
                for (int nt = 0; nt < 4; ++nt)
                    dst[((size_t)(bidx * H_ + h) * L_ + l) * D_ + nt * 16 + c] =
                        (bf16)(val[nt][reg] * inv);
            }
        }
    } else {
        #pragma unroll
        for (int mt = 0; mt < 2; ++mt)
            #pragma unroll
            for (int nt = 0; nt < 4; ++nt) {
                const int d = nt * 16 + c;
                const float bb = bias[n0 + d];
                const int l = l0 + mt * 16 + quad * 4;
                bf16x4 o;
                #pragma unroll
                for (int reg = 0; reg < 4; ++reg) o[reg] = (bf16)(acc[mt][nt][reg] + bb);
                *(bf16x4*)&vtb[((size_t)(bidx * H_ + h) * D_ + d) * L_ + l] = o;
            }
    }
}

// ---------------------------------------------------------------------------
// Kernel 2: flash attention v13 = EXACT v7 (best measured: 74.9 us) +
//   s_setprio(1)/(0) around the compute cluster ONLY (zero register state
//   added — isolates the R6 confound; m191: +4-7% on independent-block attn).
// ---------------------------------------------------------------------------
__global__ __launch_bounds__(256, 3) void flash_mfma(
    const bf16* __restrict__ q, const bf16* __restrict__ k,
    const bf16* __restrict__ vt, const float* __restrict__ bias,
    const float* __restrict__ sml,
    bf16* __restrict__ aoh, bf16* __restrict__ aol)
{
    __shared__ __align__(16) bf16 Ks0 [64][72];
    __shared__ __align__(16) bf16 Ks1 [64][72];
    __shared__ __align__(16) bf16 Vts0[64][72];
    __shared__ __align__(16) bf16 Vts1[64][72];

    const int t    = threadIdx.x;
    const int w    = t >> 6;
    const int lane = t & 63;
    const int quad = lane >> 4;
    const int c    = lane & 15;
    const int q0   = blockIdx.x * 64;
    const int bh   = blockIdx.y;
    const int h    = bh % H_;
    const int b    = bh / H_;
    const size_t base  = (size_t)bh * L_ * D_;
    const size_t vbase = (size_t)bh * D_ * L_;
    const int qrow = q0 + w * 16 + c;      // this lane's q index (column of S^T)

    const float FMAX = expf(fminf(sml[h], MAXLOG)) + 8.0f;

    // Q B-fragments straight from global, held for the whole sweep.
    bf16x8 qf[2];
    qf[0] = *(const bf16x8*)&q[base + (size_t)qrow * D_ + quad * 8];
    qf[1] = *(const bf16x8*)&q[base + (size_t)qrow * D_ + 32 + quad * 8];

    // staging indices (coalesced b128)
    const int r0  = t >> 3,         c00 = (t & 7) * 8;
    const int r1  = (t + 256) >> 3, c01 = ((t + 256) & 7) * 8;

    const size_t brow = (size_t)qrow * L_ + 4 * quad;

    float l_acc = 0.f;
    f32x4 o[4];
    #pragma unroll
    for (int dt = 0; dt < 4; ++dt) o[dt] = (f32x4){0.f, 0.f, 0.f, 0.f};

    bf16x8 kreg[2], vreg[2];
    f32x4  bregA[4], bregB[4];

    // prologue: tile 0 -> regs -> LDS buf0; tile 1 -> regs; bias 0/1 -> regs
    kreg[0] = *(const bf16x8*)&k [base  + (size_t)r0 * D_ + c00];
    kreg[1] = *(const bf16x8*)&k [base  + (size_t)r1 * D_ + c01];
    vreg[0] = *(const bf16x8*)&vt[vbase + (size_t)r0 * L_ + c00];
    vreg[1] = *(const bf16x8*)&vt[vbase + (size_t)r1 * L_ + c01];
    #pragma unroll
    for (int s = 0; s < 4; ++s)
        bregA[s] = *(const f32x4*)&bias[brow + 16 * s];

    *(bf16x8*)&Ks0 [r0][c00] = kreg[0];
    *(bf16x8*)&Ks0 [r1][c01] = kreg[1];
    *(bf16x8*)&Vts0[r0][c00] = vreg[0];
    *(bf16x8*)&Vts0[r1][c01] = vreg[1];

    kreg[0] = *(const bf16x8*)&k [base  + (size_t)(64 + r0) * D_ + c00];
    kreg[1] = *(const bf16x8*)&k [base  + (size_t)(64 + r1) * D_ + c01];
    vreg[0] = *(const bf16x8*)&vt[vbase + (size_t)r0 * L_ + 64 + c00];
    vreg[1] = *(const bf16x8*)&vt[vbase + (size_t)r1 * L_ + 64 + c01];
    #pragma unroll
    for (int s = 0; s < 4; ++s)
        bregB[s] = *(const f32x4*)&bias[brow + 64 + 16 * s];
    __syncthreads();

// One 64-k tile: stage tile IT+1 from regs, prefetch tile IT+2 into regs,
// compute tile IT (setprio-wrapped), single barrier at the end.
#define FSTEP(KS_C, VT_C, KS_N, VT_N, BC, IT) do {                               \
    if ((IT) + 1 < 32) {                                                         \
        *(bf16x8*)&KS_N [r0][c00] = kreg[0];                                     \
        *(bf16x8*)&KS_N [r1][c01] = kreg[1];                                     \
        *(bf16x8*)&VT_N [r0][c00] = vreg[0];                                     \
        *(bf16x8*)&VT_N [r1][c01] = vreg[1];                                     \
    }                                                                            \
    f32x4 st[4];                                                                 \
    _Pragma("unroll") for (int s = 0; s < 4; ++s) st[s] = BC[s];                 \
    if ((IT) + 2 < 32) {                                                         \
        const int kp = ((IT) + 2) * 64;                                          \
        kreg[0] = *(const bf16x8*)&k [base  + (size_t)(kp + r0) * D_ + c00];     \
        kreg[1] = *(const bf16x8*)&k [base  + (size_t)(kp + r1) * D_ + c01];     \
        vreg[0] = *(const bf16x8*)&vt[vbase + (size_t)r0 * L_ + kp + c00];       \
        vreg[1] = *(const bf16x8*)&vt[vbase + (size_t)r1 * L_ + kp + c01];       \
        _Pragma("unroll") for (int s = 0; s < 4; ++s)                            \
            BC[s] = *(const f32x4*)&bias[brow + kp + 16 * s];                    \
    }                                                                            \
    __builtin_amdgcn_s_setprio(1);                                               \
    _Pragma("unroll") for (int ks = 0; ks < 2; ++ks)                             \
        _Pragma("unroll") for (int s = 0; s < 4; ++s) {                          \
            const bf16x8 kf = *(const bf16x8*)&KS_C[s*16 + c][ks*32 + quad*8];   \
            st[s] = __builtin_amdgcn_mfma_f32_16x16x32_bf16(kf, qf[ks], st[s], 0, 0, 0); \
        }                                                                        \
    bf16x4 pf[4];                                                                \
    _Pragma("unroll") for (int s = 0; s < 4; ++s)                                \
        _Pragma("unroll") for (int r = 0; r < 4; ++r) {                          \
            const float pv = __expf(st[s][r] - FMAX);                            \
            l_acc += pv;                                                         \
            pf[s][r] = (bf16)pv;                                                 \
        }                                                                        \
    _Pragma("unroll") for (int s = 0; s < 4; ++s)                                \
        _Pragma("unroll") for (int dt = 0; dt < 4; ++dt) {                       \
            const bf16x4 vfr = *(const bf16x4*)&VT_C[dt*16 + c][16*s + 4*quad];  \
            o[dt] = mfma16(vfr, pf[s], o[dt]);                                   \
        }                                                                        \
    __builtin_amdgcn_s_setprio(0);                                               \
    __syncthreads();                                                             \
} while (0)

    for (int it = 0; it < 32; it += 2) {
        FSTEP(Ks0, Vts0, Ks1, Vts1, bregA, it);
        FSTEP(Ks1, Vts1, Ks0, Vts0, bregB, it + 1);
    }
#undef FSTEP

    // l: lane holds k-rows 4*quad+0..3 of every tile; reduce across quads.
    float rs = l_acc;
    rs += __shfl_xor(rs, 16);
    rs += __shfl_xor(rs, 32);
    const float linv = 1.0f / rs;

    const size_t obase = ((size_t)(b * L_ + qrow)) * C_ + h * 64;
    #pragma unroll
    for (int dt = 0; dt < 4; ++dt) {
        bf16x4 hv, lv;
        #pragma unroll
        for (int r = 0; r < 4; ++r) {
            const float v = o[dt][r] * linv;
            hv[r] = (bf16)v;
            lv[r] = (bf16)(v - (float)hv[r]);
        }
        *(bf16x4*)&aoh[obase + dt * 16 + 4 * quad] = hv;
        *(bf16x4*)&aol[obase + dt * 16 + 4 * quad] = lv;
    }
}

// ---------------------------------------------------------------------------
// Kernel 3: projection GEMM (unchanged R7).
// ---------------------------------------------------------------------------
__global__ __launch_bounds__(256) void proj_mfma(
    const bf16* __restrict__ Ahg, const bf16* __restrict__ Alg,
    const bf16* __restrict__ Whg, const bf16* __restrict__ Wlg,
    const float* __restrict__ bias, float* __restrict__ outp)
{
    __shared__ __align__(16) bf16 Ah[64][64];
    __shared__ __align__(16) bf16 Al[64][64];
    __shared__ __align__(16) bf16 Bh[64][64];
    __shared__ __align__(16) bf16 Bl[64][64];

    const int t    = threadIdx.x;
    const int w    = t >> 6;
    const int lane = t & 63;
    const int quad = lane >> 4;
    const int c    = lane & 15;
    const int m0   = blockIdx.x * 64;
    const int n0   = blockIdx.y * 64;

    const int sr = t >> 3;
    const int sc = t & 7;
    const int sx = sc ^ (sr & 7);

    f32x4 acc[4];
    #pragma unroll
    for (int nt = 0; nt < 4; ++nt) acc[nt] = (f32x4){0.f,0.f,0.f,0.f};

    for (int kt = 0; kt < C_; kt += 64) {
        __syncthreads();
        #pragma unroll
        for (int p = 0; p < 2; ++p) {
            const size_t ga = (size_t)(m0 + 32 * p + sr) * C_ + kt + 8 * sx;
            const size_t gb = (size_t)(n0 + 32 * p + sr) * C_ + kt + 8 * sx;
            const int    lo = (p * 256 + t) * 16;
            stage16(&Ahg[ga], (char*)&Ah[0][0] + lo);
            stage16(&Alg[ga], (char*)&Al[0][0] + lo);
            stage16(&Whg[gb], (char*)&Bh[0][0] + lo);
            stage16(&Wlg[gb], (char*)&Bl[0][0] + lo);
        }
        __syncthreads();

        #pragma unroll
        for (int ks = 0; ks < 2; ++ks) {
            const int rchunk = ((4 * ks + quad) ^ (c & 7)) * 16;
            const bf16x8 ah = *(const bf16x8*)((const char*)&Ah[0][0]
                              + (size_t)(w * 16 + c) * 128 + rchunk);
            const bf16x8 al = *(const bf16x8*)((const char*)&Al[0][0]
                              + (size_t)(w * 16 + c) * 128 + rchunk);
            #pragma unroll
            for (int nt = 0; nt < 4; ++nt) {
                const bf16x8 bh = *(const bf16x8*)((const char*)&Bh[0][0]
                                  + (size_t)(nt * 16 + c) * 128 + rchunk);
                const bf16x8 bl = *(const bf16x8*)((const char*)&Bl[0][0]
                                  + (size_t)(nt * 16 + c) * 128 + rchunk);
                acc[nt] = __builtin_amdgcn_mfma_f32_16x16x32_bf16(ah, bh, acc[nt], 0, 0, 0);
                acc[nt] = __builtin_amdgcn_mfma_f32_16x16x32_bf16(ah, bl, acc[nt], 0, 0, 0);
                acc[nt] = __builtin_amdgcn_mfma_f32_16x16x32_bf16(al, bh, acc[nt], 0, 0, 0);
            }
        }
    }

    #pragma unroll
    for (int nt = 0; nt < 4; ++nt) {
        const int col = n0 + nt * 16 + c;
        const float bb = bias[col];
        #pragma unroll
        for (int reg = 0; reg < 4; ++reg) {
            const int row = m0 + w * 16 + quad * 4 + reg;
            outp[(size_t)row * C_ + col] = acc[nt][reg] + bb;
        }
    }
}

// ---------------------------------------------------------------------------
extern "C" void kernel_launch(void* const* d_in, const int* in_sizes, int n_in,
                              void* d_out, int out_size, void* d_ws, size_t ws_size,
                              hipStream_t stream)
{
    const float* x         = (const float*)d_in[0];
    const float* attn_bias = (const float*)d_in[1];
    const float* W_qkv     = (const float*)d_in[2];
    const float* b_qkv     = (const float*)d_in[3];
    const float* sml       = (const float*)d_in[4];
    const float* W_proj    = (const float*)d_in[5];
    const float* b_proj    = (const float*)d_in[6];
    float* out = (float*)d_out;

    // ws layout (bf16 elements): qb,kb,vtb | aoh,aol | Wh,Wl | xb | wqb
    bf16* qb  = (bf16*)d_ws;
    bf16* kb  = qb  + SZ_;
    bf16* vtb = kb  + SZ_;
    bf16* aoh = vtb + SZ_;
    bf16* aol = aoh + MC_;
    bf16* Wh  = aol + MC_;
    bf16* Wl  = Wh  + WP_;
    bf16* xb  = Wl  + WP_;
    bf16* wqb = xb  + MC_;

    // 0) fused prep
    prep<<<2048, 256, 0, stream>>>(
        (const float4*)x, (const float4*)W_qkv, (const float4*)W_proj,
        xb, wqb, Wh, Wl);

    // 1) QKV GEMM
    qkv_mfma<<<dim3(M_ / 128, (3 * C_) / 64), 256, 0, stream>>>(
        xb, wqb, b_qkv, sml, qb, kb, vtb);

    // 2) flash attention v13: v7 + setprio (zero added register state)
    flash_mfma<<<dim3(L_ / 64, B_ * H_), 256, 0, stream>>>(
        qb, kb, vtb, attn_bias, sml, aoh, aol);

    // 3) projection GEMM
    proj_mfma<<<dim3(M_ / 64, C_ / 64), 256, 0, stream>>>(
        aoh, aol, Wh, Wl, b_proj, out);
}

// Round 12
// 192.830 us; speedup vs baseline: 1.2234x; 1.0549x over previous
//
#include <hip/hip_runtime.h>
#include <math.h>

#define B_ 2
#define L_ 2048
#define C_ 768
#define H_ 12
#define D_ 64
#define M_ (B_ * L_)          // 4096
#define MAXLOG 4.605170185988091f   // log(100)

typedef __bf16 bf16;
typedef __bf16 bf16x4 __attribute__((ext_vector_type(4)));
typedef __bf16 bf16x8 __attribute__((ext_vector_type(8)));
typedef float  f32x4  __attribute__((ext_vector_type(4)));
typedef short  s16x4  __attribute__((ext_vector_type(4)));

// workspace element counts
#define SZ_  ((size_t)B_ * H_ * L_ * D_)   // 3,145,728 (q,k,vt each)
#define MC_  ((size_t)M_ * C_)             // 3,145,728 (x / ao)
#define WQ_  ((size_t)3 * C_ * C_)         // 1,769,472 (W_qkv)
#define WP_  ((size_t)C_ * C_)             //   589,824 (W_proj)

// K=16 bf16 MFMA. S^T accumulator layout (row=4*quad+reg, col=lane&15) equals
// this op's B-fragment layout, so P^T feeds PV directly from registers.
static __device__ __forceinline__ f32x4 mfma16(bf16x4 a, bf16x4 b, f32x4 c) {
#if __has_builtin(__builtin_amdgcn_mfma_f32_16x16x16_bf16)
    return __builtin_amdgcn_mfma_f32_16x16x16_bf16(a, b, c, 0, 0, 0);
#elif __has_builtin(__builtin_amdgcn_mfma_f32_16x16x16bf16_1k)
    return __builtin_amdgcn_mfma_f32_16x16x16bf16_1k(*(s16x4*)&a, *(s16x4*)&b, c, 0, 0, 0);
#else
    f32x4 d;
    asm("v_mfma_f32_16x16x16_bf16 %0, %1, %2, %3" : "=v"(d) : "v"(a), "v"(b), "v"(c));
    return d;
#endif
}

// 16B async global->LDS stage (GEMMs only; LDS dest linear in lane).
static __device__ __forceinline__ void stage16(const bf16* gsrc, void* ldst) {
#if __has_builtin(__builtin_amdgcn_global_load_lds)
    __builtin_amdgcn_global_load_lds(
        (const __attribute__((address_space(1))) unsigned int*)gsrc,
        (__attribute__((address_space(3))) unsigned int*)ldst, 16, 0, 0);
#else
    *(bf16x8*)ldst = *(const bf16x8*)gsrc;
#endif
}

// ---------------------------------------------------------------------------
// Kernel 0: fused prep (unchanged R7).
// ---------------------------------------------------------------------------
__global__ __launch_bounds__(256) void prep(
    const float4* __restrict__ x, const float4* __restrict__ Wq,
    const float4* __restrict__ Wp,
    bf16* __restrict__ xb, bf16* __restrict__ wqb,
    bf16* __restrict__ Wh, bf16* __restrict__ Wl)
{
    const int X4 = (int)(MC_ / 4);
    const int W4 = (int)(WQ_ / 4);
    const int S4 = (int)(WP_ / 4);
    const int total = X4 + W4 + S4;

    const int i0 = blockIdx.x * 256 + threadIdx.x;
    const int stride = gridDim.x * 256;
    for (int i = i0; i < total; i += stride) {
        if (i < X4) {
            const float4 v = x[i];
            bf16x4 o; o[0]=(bf16)v.x; o[1]=(bf16)v.y; o[2]=(bf16)v.z; o[3]=(bf16)v.w;
            *(bf16x4*)&xb[(size_t)i * 4] = o;
        } else if (i < X4 + W4) {
            const int j = i - X4;
            const float4 v = Wq[j];
            bf16x4 o; o[0]=(bf16)v.x; o[1]=(bf16)v.y; o[2]=(bf16)v.z; o[3]=(bf16)v.w;
            *(bf16x4*)&wqb[(size_t)j * 4] = o;
        } else {
            const int j = i - X4 - W4;
            const float4 v = Wp[j];
            bf16x4 h, l;
            h[0]=(bf16)v.x; l[0]=(bf16)(v.x-(float)h[0]);
            h[1]=(bf16)v.y; l[1]=(bf16)(v.y-(float)h[1]);
            h[2]=(bf16)v.z; l[2]=(bf16)(v.z-(float)h[2]);
            h[3]=(bf16)v.w; l[3]=(bf16)(v.w-(float)h[3]);
            *(bf16x4*)&Wh[(size_t)j * 4] = h;
            *(bf16x4*)&Wl[(size_t)j * 4] = l;
        }
    }
}

// ---------------------------------------------------------------------------
// Kernel 1: QKV GEMM v2 — BM=128, BN=128 (2 heads/block), BK=64.
//   2x MFMA per staged byte vs the 128x64 tile (m92->m93 ladder lever).
//   DMA staging + XOR swizzle retained. Grid 32x18 = 576 blocks.
//   Epilogue: per-head l2norm (ss split per 4-nt group, 2 scales).
// ---------------------------------------------------------------------------
__global__ __launch_bounds__(256, 3) void qkv_mfma(
    const bf16* __restrict__ A, const bf16* __restrict__ W,
    const float* __restrict__ bias, const float* __restrict__ sml,
    bf16* __restrict__ qb, bf16* __restrict__ kb, bf16* __restrict__ vtb)
{
    __shared__ __align__(16) bf16 As[128][64];   // 16 KB, linear
    __shared__ __align__(16) bf16 Bs[128][64];   // 16 KB, linear

    const int t    = threadIdx.x;
    const int w    = t >> 6;
    const int lane = t & 63;
    const int quad = lane >> 4;
    const int c    = lane & 15;
    const int m0   = blockIdx.x * 128;
    const int n0   = blockIdx.y * 128;

    const int sr = t >> 3;           // 0..31
    const int sc = t & 7;
    const int sx = sc ^ (sr & 7);    // pre-swizzled source chunk

    f32x4 acc[2][8];
    #pragma unroll
    for (int mt = 0; mt < 2; ++mt)
        #pragma unroll
        for (int nt = 0; nt < 8; ++nt) acc[mt][nt] = (f32x4){0.f,0.f,0.f,0.f};

    for (int kt = 0; kt < C_; kt += 64) {
        __syncthreads();   // prev iter's LDS reads complete before overwrite
        #pragma unroll
        for (int p = 0; p < 4; ++p)
            stage16(&A[(size_t)(m0 + 32 * p + sr) * C_ + kt + 8 * sx],
                    (char*)&As[0][0] + (p * 256 + t) * 16);
        #pragma unroll
        for (int p = 0; p < 4; ++p)
            stage16(&W[(size_t)(n0 + 32 * p + sr) * C_ + kt + 8 * sx],
                    (char*)&Bs[0][0] + (p * 256 + t) * 16);
        __syncthreads();   // vmcnt drain: staged tiles ready

        #pragma unroll
        for (int ks = 0; ks < 2; ++ks) {
            const int rchunk = ((4 * ks + quad) ^ (c & 7)) * 16;
            bf16x8 bfr[8];
            #pragma unroll
            for (int nt = 0; nt < 8; ++nt)
                bfr[nt] = *(const bf16x8*)((const char*)&Bs[0][0]
                          + (size_t)(nt * 16 + c) * 128 + rchunk);
            #pragma unroll
            for (int mt = 0; mt < 2; ++mt) {
                const bf16x8 a = *(const bf16x8*)((const char*)&As[0][0]
                                 + (size_t)(w * 32 + mt * 16 + c) * 128 + rchunk);
                #pragma unroll
                for (int nt = 0; nt < 8; ++nt)
                    acc[mt][nt] = __builtin_amdgcn_mfma_f32_16x16x32_bf16(a, bfr[nt], acc[mt][nt], 0, 0, 0);
            }
        }
    }

    const int three = blockIdx.y / 6;          // 768 % 128 == 0: no straddle
    const int hbase = (blockIdx.y % 6) * 2;    // first head of this block
    const int bidx  = m0 >> 11;
    const int l0    = (m0 & (L_ - 1)) + w * 32;

    if (three < 2) {
        bf16* dst = (three == 0) ? qb : kb;
        float scale[2];
        #pragma unroll
        for (int hp = 0; hp < 2; ++hp)
            scale[hp] = (three == 0) ? expf(fminf(sml[hbase + hp], MAXLOG)) : 1.0f;
        #pragma unroll
        for (int mt = 0; mt < 2; ++mt) {
            float val[8][4];
            float ss[2][4] = {{0.f,0.f,0.f,0.f},{0.f,0.f,0.f,0.f}};
            #pragma unroll
            for (int nt = 0; nt < 8; ++nt) {
                const float bb = bias[n0 + nt * 16 + c];
                #pragma unroll
                for (int reg = 0; reg < 4; ++reg) {
                    const float v = acc[mt][nt][reg] + bb;
                    val[nt][reg] = v;
                    ss[nt >> 2][reg] += v * v;
                }
            }
            #pragma unroll
            for (int hp = 0; hp < 2; ++hp)
                #pragma unroll
                for (int reg = 0; reg < 4; ++reg) {
                    float s = ss[hp][reg];
                    #pragma unroll
                    for (int off = 1; off < 16; off <<= 1) s += __shfl_xor(s, off, 16);
                    const float inv = scale[hp] / fmaxf(sqrtf(s), 1e-12f);
                    const int l = l0 + mt * 16 + quad * 4 + reg;
                    const int h = hbase + hp;
                    #pragma unroll
                    for (int nt4 = 0; nt4 < 4; ++nt4)
                        dst[((size_t)(bidx * H_ + h) * L_ + l) * D_ + nt4 * 16 + c] =
                            (bf16)(val[hp * 4 + nt4][reg] * inv);
                }
        }
    } else {
        #pragma unroll
        for (int mt = 0; mt < 2; ++mt)
            #pragma unroll
            for (int nt = 0; nt < 8; ++nt) {
                const int h = hbase + (nt >> 2);
                const int d = (nt & 3) * 16 + c;
                const float bb = bias[n0 + nt * 16 + c];
                const int l = l0 + mt * 16 + quad * 4;
                bf16x4 ov;
                #pragma unroll
                for (int reg = 0; reg < 4; ++reg) ov[reg] = (bf16)(acc[mt][nt][reg] + bb);
                *(bf16x4*)&vtb[((size_t)(bidx * H_ + h) * D_ + d) * L_ + l] = ov;
            }
    }
}

// ---------------------------------------------------------------------------
// Kernel 2: flash attention — EXACT v7 (structural plateau: 74.9-75.8 us
//   across 4 structures; setprio null (R11), q-blocking spills (R6/R9),
//   BK=32 doubles step overhead (R10), 6-wave/CU starves TLP (R3)).
// ---------------------------------------------------------------------------
__global__ __launch_bounds__(256, 3) void flash_mfma(
    const bf16* __restrict__ q, const bf16* __restrict__ k,
    const bf16* __restrict__ vt, const float* __restrict__ bias,
    const float* __restrict__ sml,
    bf16* __restrict__ aoh, bf16* __restrict__ aol)
{
    __shared__ __align__(16) bf16 Ks0 [64][72];
    __shared__ __align__(16) bf16 Ks1 [64][72];
    __shared__ __align__(16) bf16 Vts0[64][72];
    __shared__ __align__(16) bf16 Vts1[64][72];

    const int t    = threadIdx.x;
    const int w    = t >> 6;
    const int lane = t & 63;
    const int quad = lane >> 4;
    const int c    = lane & 15;
    const int q0   = blockIdx.x * 64;
    const int bh   = blockIdx.y;
    const int h    = bh % H_;
    const int b    = bh / H_;
    const size_t base  = (size_t)bh * L_ * D_;
    const size_t vbase = (size_t)bh * D_ * L_;
    const int qrow = q0 + w * 16 + c;      // this lane's q index (column of S^T)

    const float FMAX = expf(fminf(sml[h], MAXLOG)) + 8.0f;

    // Q B-fragments straight from global, held for the whole sweep.
    bf16x8 qf[2];
    qf[0] = *(const bf16x8*)&q[base + (size_t)qrow * D_ + quad * 8];
    qf[1] = *(const bf16x8*)&q[base + (size_t)qrow * D_ + 32 + quad * 8];

    // staging indices (coalesced b128)
    const int r0  = t >> 3,         c00 = (t & 7) * 8;
    const int r1  = (t + 256) >> 3, c01 = ((t + 256) & 7) * 8;

    const size_t brow = (size_t)qrow * L_ + 4 * quad;

    float l_acc = 0.f;
    f32x4 o[4];
    #pragma unroll
    for (int dt = 0; dt < 4; ++dt) o[dt] = (f32x4){0.f, 0.f, 0.f, 0.f};

    bf16x8 kreg[2], vreg[2];
    f32x4  bregA[4], bregB[4];

    // prologue: tile 0 -> regs -> LDS buf0; tile 1 -> regs; bias 0/1 -> regs
    kreg[0] = *(const bf16x8*)&k [base  + (size_t)r0 * D_ + c00];
    kreg[1] = *(const bf16x8*)&k [base  + (size_t)r1 * D_ + c01];
    vreg[0] = *(const bf16x8*)&vt[vbase + (size_t)r0 * L_ + c00];
    vreg[1] = *(const bf16x8*)&vt[vbase + (size_t)r1 * L_ + c01];
    #pragma unroll
    for (int s = 0; s < 4; ++s)
        bregA[s] = *(const f32x4*)&bias[brow + 16 * s];

    *(bf16x8*)&Ks0 [r0][c00] = kreg[0];
    *(bf16x8*)&Ks0 [r1][c01] = kreg[1];
    *(bf16x8*)&Vts0[r0][c00] = vreg[0];
    *(bf16x8*)&Vts0[r1][c01] = vreg[1];

    kreg[0] = *(const bf16x8*)&k [base  + (size_t)(64 + r0) * D_ + c00];
    kreg[1] = *(const bf16x8*)&k [base  + (size_t)(64 + r1) * D_ + c01];
    vreg[0] = *(const bf16x8*)&vt[vbase + (size_t)r0 * L_ + 64 + c00];
    vreg[1] = *(const bf16x8*)&vt[vbase + (size_t)r1 * L_ + 64 + c01];
    #pragma unroll
    for (int s = 0; s < 4; ++s)
        bregB[s] = *(const f32x4*)&bias[brow + 64 + 16 * s];
    __syncthreads();

// One 64-k tile: stage tile IT+1 from regs, prefetch tile IT+2 into regs,
// compute tile IT, single barrier at the end.
#define FSTEP(KS_C, VT_C, KS_N, VT_N, BC, IT) do {                               \
    if ((IT) + 1 < 32) {                                                         \
        *(bf16x8*)&KS_N [r0][c00] = kreg[0];                                     \
        *(bf16x8*)&KS_N [r1][c01] = kreg[1];                                     \
        *(bf16x8*)&VT_N [r0][c00] = vreg[0];                                     \
        *(bf16x8*)&VT_N [r1][c01] = vreg[1];                                     \
    }                                                                            \
    f32x4 st[4];                                                                 \
    _Pragma("unroll") for (int s = 0; s < 4; ++s) st[s] = BC[s];                 \
    if ((IT) + 2 < 32) {                                                         \
        const int kp = ((IT) + 2) * 64;                                          \
        kreg[0] = *(const bf16x8*)&k [base  + (size_t)(kp + r0) * D_ + c00];     \
        kreg[1] = *(const bf16x8*)&k [base  + (size_t)(kp + r1) * D_ + c01];     \
        vreg[0] = *(const bf16x8*)&vt[vbase + (size_t)r0 * L_ + kp + c00];       \
        vreg[1] = *(const bf16x8*)&vt[vbase + (size_t)r1 * L_ + kp + c01];       \
        _Pragma("unroll") for (int s = 0; s < 4; ++s)                            \
            BC[s] = *(const f32x4*)&bias[brow + kp + 16 * s];                    \
    }                                                                            \
    _Pragma("unroll") for (int ks = 0; ks < 2; ++ks)                             \
        _Pragma("unroll") for (int s = 0; s < 4; ++s) {                          \
            const bf16x8 kf = *(const bf16x8*)&KS_C[s*16 + c][ks*32 + quad*8];   \
            st[s] = __builtin_amdgcn_mfma_f32_16x16x32_bf16(kf, qf[ks], st[s], 0, 0, 0); \
        }                                                                        \
    bf16x4 pf[4];                                                                \
    _Pragma("unroll") for (int s = 0; s < 4; ++s)                                \
        _Pragma("unroll") for (int r = 0; r < 4; ++r) {                          \
            const float pv = __expf(st[s][r] - FMAX);                            \
            l_acc += pv;                                                         \
            pf[s][r] = (bf16)pv;                                                 \
        }                                                                        \
    _Pragma("unroll") for (int s = 0; s < 4; ++s)                                \
        _Pragma("unroll") for (int dt = 0; dt < 4; ++dt) {                       \
            const bf16x4 vfr = *(const bf16x4*)&VT_C[dt*16 + c][16*s + 4*quad];  \
            o[dt] = mfma16(vfr, pf[s], o[dt]);                                   \
        }                                                                        \
    __syncthreads();                                                             \
} while (0)

    for (int it = 0; it < 32; it += 2) {
        FSTEP(Ks0, Vts0, Ks1, Vts1, bregA, it);
        FSTEP(Ks1, Vts1, Ks0, Vts0, bregB, it + 1);
    }
#undef FSTEP

    // l: lane holds k-rows 4*quad+0..3 of every tile; reduce across quads.
    float rs = l_acc;
    rs += __shfl_xor(rs, 16);
    rs += __shfl_xor(rs, 32);
    const float linv = 1.0f / rs;

    const size_t obase = ((size_t)(b * L_ + qrow)) * C_ + h * 64;
    #pragma unroll
    for (int dt = 0; dt < 4; ++dt) {
        bf16x4 hv, lv;
        #pragma unroll
        for (int r = 0; r < 4; ++r) {
            const float v = o[dt][r] * linv;
            hv[r] = (bf16)v;
            lv[r] = (bf16)(v - (float)hv[r]);
        }
        *(bf16x4*)&aoh[obase + dt * 16 + 4 * quad] = hv;
        *(bf16x4*)&aol[obase + dt * 16 + 4 * quad] = lv;
    }
}

// ---------------------------------------------------------------------------
// Kernel 3: projection GEMM (unchanged R7).
// ---------------------------------------------------------------------------
__global__ __launch_bounds__(256) void proj_mfma(
    const bf16* __restrict__ Ahg, const bf16* __restrict__ Alg,
    const bf16* __restrict__ Whg, const bf16* __restrict__ Wlg,
    const float* __restrict__ bias, float* __restrict__ outp)
{
    __shared__ __align__(16) bf16 Ah[64][64];
    __shared__ __align__(16) bf16 Al[64][64];
    __shared__ __align__(16) bf16 Bh[64][64];
    __shared__ __align__(16) bf16 Bl[64][64];

    const int t    = threadIdx.x;
    const int w    = t >> 6;
    const int lane = t & 63;
    const int quad = lane >> 4;
    const int c    = lane & 15;
    const int m0   = blockIdx.x * 64;
    const int n0   = blockIdx.y * 64;

    const int sr = t >> 3;
    const int sc = t & 7;
    const int sx = sc ^ (sr & 7);

    f32x4 acc[4];
    #pragma unroll
    for (int nt = 0; nt < 4; ++nt) acc[nt] = (f32x4){0.f,0.f,0.f,0.f};

    for (int kt = 0; kt < C_; kt += 64) {
        __syncthreads();
        #pragma unroll
        for (int p = 0; p < 2; ++p) {
            const size_t ga = (size_t)(m0 + 32 * p + sr) * C_ + kt + 8 * sx;
            const size_t gb = (size_t)(n0 + 32 * p + sr) * C_ + kt + 8 * sx;
            const int    lo = (p * 256 + t) * 16;
            stage16(&Ahg[ga], (char*)&Ah[0][0] + lo);
            stage16(&Alg[ga], (char*)&Al[0][0] + lo);
            stage16(&Whg[gb], (char*)&Bh[0][0] + lo);
            stage16(&Wlg[gb], (char*)&Bl[0][0] + lo);
        }
        __syncthreads();

        #pragma unroll
        for (int ks = 0; ks < 2; ++ks) {
            const int rchunk = ((4 * ks + quad) ^ (c & 7)) * 16;
            const bf16x8 ah = *(const bf16x8*)((const char*)&Ah[0][0]
                              + (size_t)(w * 16 + c) * 128 + rchunk);
            const bf16x8 al = *(const bf16x8*)((const char*)&Al[0][0]
                              + (size_t)(w * 16 + c) * 128 + rchunk);
            #pragma unroll
            for (int nt = 0; nt < 4; ++nt) {
                const bf16x8 bh = *(const bf16x8*)((const char*)&Bh[0][0]
                                  + (size_t)(nt * 16 + c) * 128 + rchunk);
                const bf16x8 bl = *(const bf16x8*)((const char*)&Bl[0][0]
                                  + (size_t)(nt * 16 + c) * 128 + rchunk);
                acc[nt] = __builtin_amdgcn_mfma_f32_16x16x32_bf16(ah, bh, acc[nt], 0, 0, 0);
                acc[nt] = __builtin_amdgcn_mfma_f32_16x16x32_bf16(ah, bl, acc[nt], 0, 0, 0);
                acc[nt] = __builtin_amdgcn_mfma_f32_16x16x32_bf16(al, bh, acc[nt], 0, 0, 0);
            }
        }
    }

    #pragma unroll
    for (int nt = 0; nt < 4; ++nt) {
        const int col = n0 + nt * 16 + c;
        const float bb = bias[col];
        #pragma unroll
        for (int reg = 0; reg < 4; ++reg) {
            const int row = m0 + w * 16 + quad * 4 + reg;
            outp[(size_t)row * C_ + col] = acc[nt][reg] + bb;
        }
    }
}

// ---------------------------------------------------------------------------
extern "C" void kernel_launch(void* const* d_in, const int* in_sizes, int n_in,
                              void* d_out, int out_size, void* d_ws, size_t ws_size,
                              hipStream_t stream)
{
    const float* x         = (const float*)d_in[0];
    const float* attn_bias = (const float*)d_in[1];
    const float* W_qkv     = (const float*)d_in[2];
    const float* b_qkv     = (const float*)d_in[3];
    const float* sml       = (const float*)d_in[4];
    const float* W_proj    = (const float*)d_in[5];
    const float* b_proj    = (const float*)d_in[6];
    float* out = (float*)d_out;

    // ws layout (bf16 elements): qb,kb,vtb | aoh,aol | Wh,Wl | xb | wqb
    bf16* qb  = (bf16*)d_ws;
    bf16* kb  = qb  + SZ_;
    bf16* vtb = kb  + SZ_;
    bf16* aoh = vtb + SZ_;
    bf16* aol = aoh + MC_;
    bf16* Wh  = aol + MC_;
    bf16* Wl  = Wh  + WP_;
    bf16* xb  = Wl  + WP_;
    bf16* wqb = xb  + MC_;

    // 0) fused prep
    prep<<<2048, 256, 0, stream>>>(
        (const float4*)x, (const float4*)W_qkv, (const float4*)W_proj,
        xb, wqb, Wh, Wl);

    // 1) QKV GEMM v2: 128x128 tile (2 heads/block), grid 32x18
    qkv_mfma<<<dim3(M_ / 128, (3 * C_) / 128), 256, 0, stream>>>(
        xb, wqb, b_qkv, sml, qb, kb, vtb);

    // 2) flash attention (exact v7 — structural plateau)
    flash_mfma<<<dim3(L_ / 64, B_ * H_), 256, 0, stream>>>(
        qb, kb, vtb, attn_bias, sml, aoh, aol);

    // 3) projection GEMM
    proj_mfma<<<dim3(M_ / 64, C_ / 64), 256, 0, stream>>>(
        aoh, aol, Wh, Wl, b_proj, out);
}

// Round 14
// 191.793 us; speedup vs baseline: 1.2300x; 1.0054x over previous
//
#include <hip/hip_runtime.h>
#include <math.h>

#define B_ 2
#define L_ 2048
#define C_ 768
#define H_ 12
#define D_ 64
#define M_ (B_ * L_)          // 4096
#define MAXLOG 4.605170185988091f   // log(100)

typedef __bf16 bf16;
typedef __bf16 bf16x4 __attribute__((ext_vector_type(4)));
typedef __bf16 bf16x8 __attribute__((ext_vector_type(8)));
typedef float  f32x4  __attribute__((ext_vector_type(4)));
typedef short  s16x4  __attribute__((ext_vector_type(4)));

// workspace element counts
#define SZ_  ((size_t)B_ * H_ * L_ * D_)   // 3,145,728 (q,k,vt each)
#define MC_  ((size_t)M_ * C_)             // 3,145,728 (x / ao)
#define WQ_  ((size_t)3 * C_ * C_)         // 1,769,472 (W_qkv)
#define WP_  ((size_t)C_ * C_)             //   589,824 (W_proj)

// K=16 bf16 MFMA. S^T accumulator layout (row=4*quad+reg, col=lane&15) equals
// this op's B-fragment layout, so P^T feeds PV directly from registers.
static __device__ __forceinline__ f32x4 mfma16(bf16x4 a, bf16x4 b, f32x4 c) {
#if __has_builtin(__builtin_amdgcn_mfma_f32_16x16x16_bf16)
    return __builtin_amdgcn_mfma_f32_16x16x16_bf16(a, b, c, 0, 0, 0);
#elif __has_builtin(__builtin_amdgcn_mfma_f32_16x16x16bf16_1k)
    return __builtin_amdgcn_mfma_f32_16x16x16bf16_1k(*(s16x4*)&a, *(s16x4*)&b, c, 0, 0, 0);
#else
    f32x4 d;
    asm("v_mfma_f32_16x16x16_bf16 %0, %1, %2, %3" : "=v"(d) : "v"(a), "v"(b), "v"(c));
    return d;
#endif
}

// 16B async global->LDS stage (GEMMs only; LDS dest linear in lane).
static __device__ __forceinline__ void stage16(const bf16* gsrc, void* ldst) {
#if __has_builtin(__builtin_amdgcn_global_load_lds)
    __builtin_amdgcn_global_load_lds(
        (const __attribute__((address_space(1))) unsigned int*)gsrc,
        (__attribute__((address_space(3))) unsigned int*)ldst, 16, 0, 0);
#else
    *(bf16x8*)ldst = *(const bf16x8*)gsrc;
#endif
}

// ---------------------------------------------------------------------------
// Kernel 0: fused prep (unchanged R7).
// ---------------------------------------------------------------------------
__global__ __launch_bounds__(256) void prep(
    const float4* __restrict__ x, const float4* __restrict__ Wq,
    const float4* __restrict__ Wp,
    bf16* __restrict__ xb, bf16* __restrict__ wqb,
    bf16* __restrict__ Wh, bf16* __restrict__ Wl)
{
    const int X4 = (int)(MC_ / 4);
    const int W4 = (int)(WQ_ / 4);
    const int S4 = (int)(WP_ / 4);
    const int total = X4 + W4 + S4;

    const int i0 = blockIdx.x * 256 + threadIdx.x;
    const int stride = gridDim.x * 256;
    for (int i = i0; i < total; i += stride) {
        if (i < X4) {
            const float4 v = x[i];
            bf16x4 o; o[0]=(bf16)v.x; o[1]=(bf16)v.y; o[2]=(bf16)v.z; o[3]=(bf16)v.w;
            *(bf16x4*)&xb[(size_t)i * 4] = o;
        } else if (i < X4 + W4) {
            const int j = i - X4;
            const float4 v = Wq[j];
            bf16x4 o; o[0]=(bf16)v.x; o[1]=(bf16)v.y; o[2]=(bf16)v.z; o[3]=(bf16)v.w;
            *(bf16x4*)&wqb[(size_t)j * 4] = o;
        } else {
            const int j = i - X4 - W4;
            const float4 v = Wp[j];
            bf16x4 h, l;
            h[0]=(bf16)v.x; l[0]=(bf16)(v.x-(float)h[0]);
            h[1]=(bf16)v.y; l[1]=(bf16)(v.y-(float)h[1]);
            h[2]=(bf16)v.z; l[2]=(bf16)(v.z-(float)h[2]);
            h[3]=(bf16)v.w; l[3]=(bf16)(v.w-(float)h[3]);
            *(bf16x4*)&Wh[(size_t)j * 4] = h;
            *(bf16x4*)&Wl[(size_t)j * 4] = l;
        }
    }
}

// ---------------------------------------------------------------------------
// Kernel 1: QKV GEMM v2 (unchanged R12: 128x128 tile, 2 heads/block).
// ---------------------------------------------------------------------------
__global__ __launch_bounds__(256, 3) void qkv_mfma(
    const bf16* __restrict__ A, const bf16* __restrict__ W,
    const float* __restrict__ bias, const float* __restrict__ sml,
    bf16* __restrict__ qb, bf16* __restrict__ kb, bf16* __restrict__ vtb)
{
    __shared__ __align__(16) bf16 As[128][64];   // 16 KB, linear
    __shared__ __align__(16) bf16 Bs[128][64];   // 16 KB, linear

    const int t    = threadIdx.x;
    const int w    = t >> 6;
    const int lane = t & 63;
    const int quad = lane >> 4;
    const int c    = lane & 15;
    const int m0   = blockIdx.x * 128;
    const int n0   = blockIdx.y * 128;

    const int sr = t >> 3;           // 0..31
    const int sc = t & 7;
    const int sx = sc ^ (sr & 7);    // pre-swizzled source chunk

    f32x4 acc[2][8];
    #pragma unroll
    for (int mt = 0; mt < 2; ++mt)
        #pragma unroll
        for (int nt = 0; nt < 8; ++nt) acc[mt][nt] = (f32x4){0.f,0.f,0.f,0.f};

    for (int kt = 0; kt < C_; kt += 64) {
        __syncthreads();   // prev iter's LDS reads complete before overwrite
        #pragma unroll
        for (int p = 0; p < 4; ++p)
            stage16(&A[(size_t)(m0 + 32 * p + sr) * C_ + kt + 8 * sx],
                    (char*)&As[0][0] + (p * 256 + t) * 16);
        #pragma unroll
        for (int p = 0; p < 4; ++p)
            stage16(&W[(size_t)(n0 + 32 * p + sr) * C_ + kt + 8 * sx],
                    (char*)&Bs[0][0] + (p * 256 + t) * 16);
        __syncthreads();   // vmcnt drain: staged tiles ready

        #pragma unroll
        for (int ks = 0; ks < 2; ++ks) {
            const int rchunk = ((4 * ks + quad) ^ (c & 7)) * 16;
            bf16x8 bfr[8];
            #pragma unroll
            for (int nt = 0; nt < 8; ++nt)
                bfr[nt] = *(const bf16x8*)((const char*)&Bs[0][0]
                          + (size_t)(nt * 16 + c) * 128 + rchunk);
            #pragma unroll
            for (int mt = 0; mt < 2; ++mt) {
                const bf16x8 a = *(const bf16x8*)((const char*)&As[0][0]
                                 + (size_t)(w * 32 + mt * 16 + c) * 128 + rchunk);
                #pragma unroll
                for (int nt = 0; nt < 8; ++nt)
                    acc[mt][nt] = __builtin_amdgcn_mfma_f32_16x16x32_bf16(a, bfr[nt], acc[mt][nt], 0, 0, 0);
            }
        }
    }

    const int three = blockIdx.y / 6;          // 768 % 128 == 0: no straddle
    const int hbase = (blockIdx.y % 6) * 2;    // first head of this block
    const int bidx  = m0 >> 11;
    const int l0    = (m0 & (L_ - 1)) + w * 32;

    if (three < 2) {
        bf16* dst = (three == 0) ? qb : kb;
        float scale[2];
        #pragma unroll
        for (int hp = 0; hp < 2; ++hp)
            scale[hp] = (three == 0) ? expf(fminf(sml[hbase + hp], MAXLOG)) : 1.0f;
        #pragma unroll
        for (int mt = 0; mt < 2; ++mt) {
            float val[8][4];
            float ss[2][4] = {{0.f,0.f,0.f,0.f},{0.f,0.f,0.f,0.f}};
            #pragma unroll
            for (int nt = 0; nt < 8; ++nt) {
                const float bb = bias[n0 + nt * 16 + c];
                #pragma unroll
                for (int reg = 0; reg < 4; ++reg) {
                    const float v = acc[mt][nt][reg] + bb;
                    val[nt][reg] = v;
                    ss[nt >> 2][reg] += v * v;
                }
            }
            #pragma unroll
            for (int hp = 0; hp < 2; ++hp)
                #pragma unroll
                for (int reg = 0; reg < 4; ++reg) {
                    float s = ss[hp][reg];
                    #pragma unroll
                    for (int off = 1; off < 16; off <<= 1) s += __shfl_xor(s, off, 16);
                    const float inv = scale[hp] / fmaxf(sqrtf(s), 1e-12f);
                    const int l = l0 + mt * 16 + quad * 4 + reg;
                    const int h = hbase + hp;
                    #pragma unroll
                    for (int nt4 = 0; nt4 < 4; ++nt4)
                        dst[((size_t)(bidx * H_ + h) * L_ + l) * D_ + nt4 * 16 + c] =
                            (bf16)(val[hp * 4 + nt4][reg] * inv);
                }
        }
    } else {
        #pragma unroll
        for (int mt = 0; mt < 2; ++mt)
            #pragma unroll
            for (int nt = 0; nt < 8; ++nt) {
                const int h = hbase + (nt >> 2);
                const int d = (nt & 3) * 16 + c;
                const float bb = bias[n0 + nt * 16 + c];
                const int l = l0 + mt * 16 + quad * 4;
                bf16x4 ov;
                #pragma unroll
                for (int reg = 0; reg < 4; ++reg) ov[reg] = (bf16)(acc[mt][nt][reg] + bb);
                *(bf16x4*)&vtb[((size_t)(bidx * H_ + h) * D_ + d) * L_ + l] = ov;
            }
    }
}

// ---------------------------------------------------------------------------
// Kernel 2: flash attention — EXACT v7 (structural plateau).
// ---------------------------------------------------------------------------
__global__ __launch_bounds__(256, 3) void flash_mfma(
    const bf16* __restrict__ q, const bf16* __restrict__ k,
    const bf16* __restrict__ vt, const float* __restrict__ bias,
    const float* __restrict__ sml,
    bf16* __restrict__ aoh, bf16* __restrict__ aol)
{
    __shared__ __align__(16) bf16 Ks0 [64][72];
    __shared__ __align__(16) bf16 Ks1 [64][72];
    __shared__ __align__(16) bf16 Vts0[64][72];
    __shared__ __align__(16) bf16 Vts1[64][72];

    const int t    = threadIdx.x;
    const int w    = t >> 6;
    const int lane = t & 63;
    const int quad = lane >> 4;
    const int c    = lane & 15;
    const int q0   = blockIdx.x * 64;
    const int bh   = blockIdx.y;
    const int h    = bh % H_;
    const int b    = bh / H_;
    const size_t base  = (size_t)bh * L_ * D_;
    const size_t vbase = (size_t)bh * D_ * L_;
    const int qrow = q0 + w * 16 + c;      // this lane's q index (column of S^T)

    const float FMAX = expf(fminf(sml[h], MAXLOG)) + 8.0f;

    // Q B-fragments straight from global, held for the whole sweep.
    bf16x8 qf[2];
    qf[0] = *(const bf16x8*)&q[base + (size_t)qrow * D_ + quad * 8];
    qf[1] = *(const bf16x8*)&q[base + (size_t)qrow * D_ + 32 + quad * 8];

    // staging indices (coalesced b128)
    const int r0  = t >> 3,         c00 = (t & 7) * 8;
    const int r1  = (t + 256) >> 3, c01 = ((t + 256) & 7) * 8;

    const size_t brow = (size_t)qrow * L_ + 4 * quad;

    float l_acc = 0.f;
    f32x4 o[4];
    #pragma unroll
    for (int dt = 0; dt < 4; ++dt) o[dt] = (f32x4){0.f, 0.f, 0.f, 0.f};

    bf16x8 kreg[2], vreg[2];
    f32x4  bregA[4], bregB[4];

    // prologue: tile 0 -> regs -> LDS buf0; tile 1 -> regs; bias 0/1 -> regs
    kreg[0] = *(const bf16x8*)&k [base  + (size_t)r0 * D_ + c00];
    kreg[1] = *(const bf16x8*)&k [base  + (size_t)r1 * D_ + c01];
    vreg[0] = *(const bf16x8*)&vt[vbase + (size_t)r0 * L_ + c00];
    vreg[1] = *(const bf16x8*)&vt[vbase + (size_t)r1 * L_ + c01];
    #pragma unroll
    for (int s = 0; s < 4; ++s)
        bregA[s] = *(const f32x4*)&bias[brow + 16 * s];

    *(bf16x8*)&Ks0 [r0][c00] = kreg[0];
    *(bf16x8*)&Ks0 [r1][c01] = kreg[1];
    *(bf16x8*)&Vts0[r0][c00] = vreg[0];
    *(bf16x8*)&Vts0[r1][c01] = vreg[1];

    kreg[0] = *(const bf16x8*)&k [base  + (size_t)(64 + r0) * D_ + c00];
    kreg[1] = *(const bf16x8*)&k [base  + (size_t)(64 + r1) * D_ + c01];
    vreg[0] = *(const bf16x8*)&vt[vbase + (size_t)r0 * L_ + 64 + c00];
    vreg[1] = *(const bf16x8*)&vt[vbase + (size_t)r1 * L_ + 64 + c01];
    #pragma unroll
    for (int s = 0; s < 4; ++s)
        bregB[s] = *(const f32x4*)&bias[brow + 64 + 16 * s];
    __syncthreads();

// One 64-k tile: stage tile IT+1 from regs, prefetch tile IT+2 into regs,
// compute tile IT, single barrier at the end.
#define FSTEP(KS_C, VT_C, KS_N, VT_N, BC, IT) do {                               \
    if ((IT) + 1 < 32) {                                                         \
        *(bf16x8*)&KS_N [r0][c00] = kreg[0];                                     \
        *(bf16x8*)&KS_N [r1][c01] = kreg[1];                                     \
        *(bf16x8*)&VT_N [r0][c00] = vreg[0];                                     \
        *(bf16x8*)&VT_N [r1][c01] = vreg[1];                                     \
    }                                                                            \
    f32x4 st[4];                                                                 \
    _Pragma("unroll") for (int s = 0; s < 4; ++s) st[s] = BC[s];                 \
    if ((IT) + 2 < 32) {                                                         \
        const int kp = ((IT) + 2) * 64;                                          \
        kreg[0] = *(const bf16x8*)&k [base  + (size_t)(kp + r0) * D_ + c00];     \
        kreg[1] = *(const bf16x8*)&k [base  + (size_t)(kp + r1) * D_ + c01];     \
        vreg[0] = *(const bf16x8*)&vt[vbase + (size_t)r0 * L_ + kp + c00];       \
        vreg[1] = *(const bf16x8*)&vt[vbase + (size_t)r1 * L_ + kp + c01];       \
        _Pragma("unroll") for (int s = 0; s < 4; ++s)                            \
            BC[s] = *(const f32x4*)&bias[brow + kp + 16 * s];                    \
    }                                                                            \
    _Pragma("unroll") for (int ks = 0; ks < 2; ++ks)                             \
        _Pragma("unroll") for (int s = 0; s < 4; ++s) {                          \
            const bf16x8 kf = *(const bf16x8*)&KS_C[s*16 + c][ks*32 + quad*8];   \
            st[s] = __builtin_amdgcn_mfma_f32_16x16x32_bf16(kf, qf[ks], st[s], 0, 0, 0); \
        }                                                                        \
    bf16x4 pf[4];                                                                \
    _Pragma("unroll") for (int s = 0; s < 4; ++s)                                \
        _Pragma("unroll") for (int r = 0; r < 4; ++r) {                          \
            const float pv = __expf(st[s][r] - FMAX);                            \
            l_acc += pv;                                                         \
            pf[s][r] = (bf16)pv;                                                 \
        }                                                                        \
    _Pragma("unroll") for (int s = 0; s < 4; ++s)                                \
        _Pragma("unroll") for (int dt = 0; dt < 4; ++dt) {                       \
            const bf16x4 vfr = *(const bf16x4*)&VT_C[dt*16 + c][16*s + 4*quad];  \
            o[dt] = mfma16(vfr, pf[s], o[dt]);                                   \
        }                                                                        \
    __syncthreads();                                                             \
} while (0)

    for (int it = 0; it < 32; it += 2) {
        FSTEP(Ks0, Vts0, Ks1, Vts1, bregA, it);
        FSTEP(Ks1, Vts1, Ks0, Vts0, bregB, it + 1);
    }
#undef FSTEP

    // l: lane holds k-rows 4*quad+0..3 of every tile; reduce across quads.
    float rs = l_acc;
    rs += __shfl_xor(rs, 16);
    rs += __shfl_xor(rs, 32);
    const float linv = 1.0f / rs;

    const size_t obase = ((size_t)(b * L_ + qrow)) * C_ + h * 64;
    #pragma unroll
    for (int dt = 0; dt < 4; ++dt) {
        bf16x4 hv, lv;
        #pragma unroll
        for (int r = 0; r < 4; ++r) {
            const float v = o[dt][r] * linv;
            hv[r] = (bf16)v;
            lv[r] = (bf16)(v - (float)hv[r]);
        }
        *(bf16x4*)&aoh[obase + dt * 16 + 4 * quad] = hv;
        *(bf16x4*)&aol[obase + dt * 16 + 4 * quad] = lv;
    }
}

// ---------------------------------------------------------------------------
// Kernel 3: projection GEMM v2 — BM=128, BN=64 (R12's density lever):
//   per k-step a wave does 24 MFMAs on 12 b128 reads (was 12 on 10);
//   B-fragments loaded once per ks, reused across both m-tiles.
//   Grid 32x12 = 384; LDS 48 KB (3/CU residency possible).
// ---------------------------------------------------------------------------
__global__ __launch_bounds__(256) void proj_mfma(
    const bf16* __restrict__ Ahg, const bf16* __restrict__ Alg,
    const bf16* __restrict__ Whg, const bf16* __restrict__ Wlg,
    const float* __restrict__ bias, float* __restrict__ outp)
{
    __shared__ __align__(16) bf16 Ah[128][64];   // 16 KB
    __shared__ __align__(16) bf16 Al[128][64];   // 16 KB
    __shared__ __align__(16) bf16 Bh[64][64];    //  8 KB
    __shared__ __align__(16) bf16 Bl[64][64];    //  8 KB

    const int t    = threadIdx.x;
    const int w    = t >> 6;
    const int lane = t & 63;
    const int quad = lane >> 4;
    const int c    = lane & 15;
    const int m0   = blockIdx.x * 128;
    const int n0   = blockIdx.y * 64;

    const int sr = t >> 3;           // 0..31
    const int sc = t & 7;
    const int sx = sc ^ (sr & 7);

    f32x4 acc[2][4];
    #pragma unroll
    for (int mt = 0; mt < 2; ++mt)
        #pragma unroll
        for (int nt = 0; nt < 4; ++nt) acc[mt][nt] = (f32x4){0.f,0.f,0.f,0.f};

    for (int kt = 0; kt < C_; kt += 64) {
        __syncthreads();
        #pragma unroll
        for (int p = 0; p < 4; ++p) {
            const size_t ga = (size_t)(m0 + 32 * p + sr) * C_ + kt + 8 * sx;
            const int    lo = (p * 256 + t) * 16;
            stage16(&Ahg[ga], (char*)&Ah[0][0] + lo);
            stage16(&Alg[ga], (char*)&Al[0][0] + lo);
        }
        #pragma unroll
        for (int p = 0; p < 2; ++p) {
            const size_t gb = (size_t)(n0 + 32 * p + sr) * C_ + kt + 8 * sx;
            const int    lo = (p * 256 + t) * 16;
            stage16(&Whg[gb], (char*)&Bh[0][0] + lo);
            stage16(&Wlg[gb], (char*)&Bl[0][0] + lo);
        }
        __syncthreads();

        #pragma unroll
        for (int ks = 0; ks < 2; ++ks) {
            const int rchunk = ((4 * ks + quad) ^ (c & 7)) * 16;
            bf16x8 bh[4], bl[4];
            #pragma unroll
            for (int nt = 0; nt < 4; ++nt) {
                bh[nt] = *(const bf16x8*)((const char*)&Bh[0][0]
                         + (size_t)(nt * 16 + c) * 128 + rchunk);
                bl[nt] = *(const bf16x8*)((const char*)&Bl[0][0]
                         + (size_t)(nt * 16 + c) * 128 + rchunk);
            }
            #pragma unroll
            for (int mt = 0; mt < 2; ++mt) {
                const bf16x8 ah = *(const bf16x8*)((const char*)&Ah[0][0]
                                  + (size_t)(w * 32 + mt * 16 + c) * 128 + rchunk);
                const bf16x8 al = *(const bf16x8*)((const char*)&Al[0][0]
                                  + (size_t)(w * 32 + mt * 16 + c) * 128 + rchunk);
                #pragma unroll
                for (int nt = 0; nt < 4; ++nt) {
                    acc[mt][nt] = __builtin_amdgcn_mfma_f32_16x16x32_bf16(ah, bh[nt], acc[mt][nt], 0, 0, 0);
                    acc[mt][nt] = __builtin_amdgcn_mfma_f32_16x16x32_bf16(ah, bl[nt], acc[mt][nt], 0, 0, 0);
                    acc[mt][nt] = __builtin_amdgcn_mfma_f32_16x16x32_bf16(al, bh[nt], acc[mt][nt], 0, 0, 0);
                }
            }
        }
    }

    #pragma unroll
    for (int mt = 0; mt < 2; ++mt)
        #pragma unroll
        for (int nt = 0; nt < 4; ++nt) {
            const int col = n0 + nt * 16 + c;
            const float bb = bias[col];
            #pragma unroll
            for (int reg = 0; reg < 4; ++reg) {
                const int row = m0 + w * 32 + mt * 16 + quad * 4 + reg;
                outp[(size_t)row * C_ + col] = acc[mt][nt][reg] + bb;
            }
        }
}

// ---------------------------------------------------------------------------
extern "C" void kernel_launch(void* const* d_in, const int* in_sizes, int n_in,
                              void* d_out, int out_size, void* d_ws, size_t ws_size,
                              hipStream_t stream)
{
    const float* x         = (const float*)d_in[0];
    const float* attn_bias = (const float*)d_in[1];
    const float* W_qkv     = (const float*)d_in[2];
    const float* b_qkv     = (const float*)d_in[3];
    const float* sml       = (const float*)d_in[4];
    const float* W_proj    = (const float*)d_in[5];
    const float* b_proj    = (const float*)d_in[6];
    float* out = (float*)d_out;

    // ws layout (bf16 elements): qb,kb,vtb | aoh,aol | Wh,Wl | xb | wqb
    bf16* qb  = (bf16*)d_ws;
    bf16* kb  = qb  + SZ_;
    bf16* vtb = kb  + SZ_;
    bf16* aoh = vtb + SZ_;
    bf16* aol = aoh + MC_;
    bf16* Wh  = aol + MC_;
    bf16* Wl  = Wh  + WP_;
    bf16* xb  = Wl  + WP_;
    bf16* wqb = xb  + MC_;

    // 0) fused prep
    prep<<<2048, 256, 0, stream>>>(
        (const float4*)x, (const float4*)W_qkv, (const float4*)W_proj,
        xb, wqb, Wh, Wl);

    // 1) QKV GEMM v2: 128x128 tile (2 heads/block), grid 32x18
    qkv_mfma<<<dim3(M_ / 128, (3 * C_) / 128), 256, 0, stream>>>(
        xb, wqb, b_qkv, sml, qb, kb, vtb);

    // 2) flash attention (exact v7 — structural plateau)
    flash_mfma<<<dim3(L_ / 64, B_ * H_), 256, 0, stream>>>(
        qb, kb, vtb, attn_bias, sml, aoh, aol);

    // 3) projection GEMM v2: BM=128, BN=64, grid 32x12
    proj_mfma<<<dim3(M_ / 128, C_ / 64), 256, 0, stream>>>(
        aoh, aol, Wh, Wl, b_proj, out);
}

// Round 15
// 188.766 us; speedup vs baseline: 1.2497x; 1.0160x over previous
//
#include <hip/hip_runtime.h>
#include <math.h>

#define B_ 2
#define L_ 2048
#define C_ 768
#define H_ 12
#define D_ 64
#define M_ (B_ * L_)          // 4096
#define MAXLOG 4.605170185988091f   // log(100)

typedef __bf16 bf16;
typedef __bf16 bf16x4 __attribute__((ext_vector_type(4)));
typedef __bf16 bf16x8 __attribute__((ext_vector_type(8)));
typedef _Float16 f16;
typedef _Float16 f16x4 __attribute__((ext_vector_type(4)));
typedef _Float16 f16x8 __attribute__((ext_vector_type(8)));
typedef float  f32x4  __attribute__((ext_vector_type(4)));
typedef short  s16x4  __attribute__((ext_vector_type(4)));

// workspace element counts
#define SZ_  ((size_t)B_ * H_ * L_ * D_)   // 3,145,728 (q,k,vt each)
#define MC_  ((size_t)M_ * C_)             // 3,145,728 (x / ao)
#define WQ_  ((size_t)3 * C_ * C_)         // 1,769,472 (W_qkv)
#define WP_  ((size_t)C_ * C_)             //   589,824 (W_proj)

// K=16 bf16 MFMA. S^T accumulator layout (row=4*quad+reg, col=lane&15) equals
// this op's B-fragment layout, so P^T feeds PV directly from registers.
static __device__ __forceinline__ f32x4 mfma16(bf16x4 a, bf16x4 b, f32x4 c) {
#if __has_builtin(__builtin_amdgcn_mfma_f32_16x16x16_bf16)
    return __builtin_amdgcn_mfma_f32_16x16x16_bf16(a, b, c, 0, 0, 0);
#elif __has_builtin(__builtin_amdgcn_mfma_f32_16x16x16bf16_1k)
    return __builtin_amdgcn_mfma_f32_16x16x16bf16_1k(*(s16x4*)&a, *(s16x4*)&b, c, 0, 0, 0);
#else
    f32x4 d;
    asm("v_mfma_f32_16x16x16_bf16 %0, %1, %2, %3" : "=v"(d) : "v"(a), "v"(b), "v"(c));
    return d;
#endif
}

// 16B async global->LDS stage (GEMMs only; LDS dest linear in lane).
static __device__ __forceinline__ void stage16(const void* gsrc, void* ldst) {
#if __has_builtin(__builtin_amdgcn_global_load_lds)
    __builtin_amdgcn_global_load_lds(
        (const __attribute__((address_space(1))) unsigned int*)gsrc,
        (__attribute__((address_space(3))) unsigned int*)ldst, 16, 0, 0);
#else
    *(bf16x8*)ldst = *(const bf16x8*)gsrc;
#endif
}

// ---------------------------------------------------------------------------
// Kernel 0: fused prep. W_proj now single f16 cvt (no hi/lo split — proj v3
// carries precision in the A operand instead).
// ---------------------------------------------------------------------------
__global__ __launch_bounds__(256) void prep(
    const float4* __restrict__ x, const float4* __restrict__ Wq,
    const float4* __restrict__ Wp,
    bf16* __restrict__ xb, bf16* __restrict__ wqb,
    f16* __restrict__ Wf)
{
    const int X4 = (int)(MC_ / 4);
    const int W4 = (int)(WQ_ / 4);
    const int S4 = (int)(WP_ / 4);
    const int total = X4 + W4 + S4;

    const int i0 = blockIdx.x * 256 + threadIdx.x;
    const int stride = gridDim.x * 256;
    for (int i = i0; i < total; i += stride) {
        if (i < X4) {
            const float4 v = x[i];
            bf16x4 o; o[0]=(bf16)v.x; o[1]=(bf16)v.y; o[2]=(bf16)v.z; o[3]=(bf16)v.w;
            *(bf16x4*)&xb[(size_t)i * 4] = o;
        } else if (i < X4 + W4) {
            const int j = i - X4;
            const float4 v = Wq[j];
            bf16x4 o; o[0]=(bf16)v.x; o[1]=(bf16)v.y; o[2]=(bf16)v.z; o[3]=(bf16)v.w;
            *(bf16x4*)&wqb[(size_t)j * 4] = o;
        } else {
            const int j = i - X4 - W4;
            const float4 v = Wp[j];
            f16x4 o; o[0]=(f16)v.x; o[1]=(f16)v.y; o[2]=(f16)v.z; o[3]=(f16)v.w;
            *(f16x4*)&Wf[(size_t)j * 4] = o;
        }
    }
}

// ---------------------------------------------------------------------------
// Kernel 1: QKV GEMM v2 (unchanged R12: 128x128 tile, 2 heads/block).
// ---------------------------------------------------------------------------
__global__ __launch_bounds__(256, 3) void qkv_mfma(
    const bf16* __restrict__ A, const bf16* __restrict__ W,
    const float* __restrict__ bias, const float* __restrict__ sml,
    bf16* __restrict__ qb, bf16* __restrict__ kb, bf16* __restrict__ vtb)
{
    __shared__ __align__(16) bf16 As[128][64];   // 16 KB, linear
    __shared__ __align__(16) bf16 Bs[128][64];   // 16 KB, linear

    const int t    = threadIdx.x;
    const int w    = t >> 6;
    const int lane = t & 63;
    const int quad = lane >> 4;
    const int c    = lane & 15;
    const int m0   = blockIdx.x * 128;
    const int n0   = blockIdx.y * 128;

    const int sr = t >> 3;           // 0..31
    const int sc = t & 7;
    const int sx = sc ^ (sr & 7);    // pre-swizzled source chunk

    f32x4 acc[2][8];
    #pragma unroll
    for (int mt = 0; mt < 2; ++mt)
        #pragma unroll
        for (int nt = 0; nt < 8; ++nt) acc[mt][nt] = (f32x4){0.f,0.f,0.f,0.f};

    for (int kt = 0; kt < C_; kt += 64) {
        __syncthreads();   // prev iter's LDS reads complete before overwrite
        #pragma unroll
        for (int p = 0; p < 4; ++p)
            stage16(&A[(size_t)(m0 + 32 * p + sr) * C_ + kt + 8 * sx],
                    (char*)&As[0][0] + (p * 256 + t) * 16);
        #pragma unroll
        for (int p = 0; p < 4; ++p)
            stage16(&W[(size_t)(n0 + 32 * p + sr) * C_ + kt + 8 * sx],
                    (char*)&Bs[0][0] + (p * 256 + t) * 16);
        __syncthreads();   // vmcnt drain: staged tiles ready

        #pragma unroll
        for (int ks = 0; ks < 2; ++ks) {
            const int rchunk = ((4 * ks + quad) ^ (c & 7)) * 16;
            bf16x8 bfr[8];
            #pragma unroll
            for (int nt = 0; nt < 8; ++nt)
                bfr[nt] = *(const bf16x8*)((const char*)&Bs[0][0]
                          + (size_t)(nt * 16 + c) * 128 + rchunk);
            #pragma unroll
            for (int mt = 0; mt < 2; ++mt) {
                const bf16x8 a = *(const bf16x8*)((const char*)&As[0][0]
                                 + (size_t)(w * 32 + mt * 16 + c) * 128 + rchunk);
                #pragma unroll
                for (int nt = 0; nt < 8; ++nt)
                    acc[mt][nt] = __builtin_amdgcn_mfma_f32_16x16x32_bf16(a, bfr[nt], acc[mt][nt], 0, 0, 0);
            }
        }
    }

    const int three = blockIdx.y / 6;          // 768 % 128 == 0: no straddle
    const int hbase = (blockIdx.y % 6) * 2;    // first head of this block
    const int bidx  = m0 >> 11;
    const int l0    = (m0 & (L_ - 1)) + w * 32;

    if (three < 2) {
        bf16* dst = (three == 0) ? qb : kb;
        float scale[2];
        #pragma unroll
        for (int hp = 0; hp < 2; ++hp)
            scale[hp] = (three == 0) ? expf(fminf(sml[hbase + hp], MAXLOG)) : 1.0f;
        #pragma unroll
        for (int mt = 0; mt < 2; ++mt) {
            float val[8][4];
            float ss[2][4] = {{0.f,0.f,0.f,0.f},{0.f,0.f,0.f,0.f}};
            #pragma unroll
            for (int nt = 0; nt < 8; ++nt) {
                const float bb = bias[n0 + nt * 16 + c];
                #pragma unroll
                for (int reg = 0; reg < 4; ++reg) {
                    const float v = acc[mt][nt][reg] + bb;
                    val[nt][reg] = v;
                    ss[nt >> 2][reg] += v * v;
                }
            }
            #pragma unroll
            for (int hp = 0; hp < 2; ++hp)
                #pragma unroll
                for (int reg = 0; reg < 4; ++reg) {
                    float s = ss[hp][reg];
                    #pragma unroll
                    for (int off = 1; off < 16; off <<= 1) s += __shfl_xor(s, off, 16);
                    const float inv = scale[hp] / fmaxf(sqrtf(s), 1e-12f);
                    const int l = l0 + mt * 16 + quad * 4 + reg;
                    const int h = hbase + hp;
                    #pragma unroll
                    for (int nt4 = 0; nt4 < 4; ++nt4)
                        dst[((size_t)(bidx * H_ + h) * L_ + l) * D_ + nt4 * 16 + c] =
                            (bf16)(val[hp * 4 + nt4][reg] * inv);
                }
        }
    } else {
        #pragma unroll
        for (int mt = 0; mt < 2; ++mt)
            #pragma unroll
            for (int nt = 0; nt < 8; ++nt) {
                const int h = hbase + (nt >> 2);
                const int d = (nt & 3) * 16 + c;
                const float bb = bias[n0 + nt * 16 + c];
                const int l = l0 + mt * 16 + quad * 4;
                bf16x4 ov;
                #pragma unroll
                for (int reg = 0; reg < 4; ++reg) ov[reg] = (bf16)(acc[mt][nt][reg] + bb);
                *(bf16x4*)&vtb[((size_t)(bidx * H_ + h) * D_ + d) * L_ + l] = ov;
            }
    }
}

// ---------------------------------------------------------------------------
// Kernel 2: flash attention — v7 structure (plateau); epilogue now emits
//   f16 hi/lo (22-bit pair, more precise than the old bf16 pair) for proj v3.
// ---------------------------------------------------------------------------
__global__ __launch_bounds__(256, 3) void flash_mfma(
    const bf16* __restrict__ q, const bf16* __restrict__ k,
    const bf16* __restrict__ vt, const float* __restrict__ bias,
    const float* __restrict__ sml,
    f16* __restrict__ aoh, f16* __restrict__ aol)
{
    __shared__ __align__(16) bf16 Ks0 [64][72];
    __shared__ __align__(16) bf16 Ks1 [64][72];
    __shared__ __align__(16) bf16 Vts0[64][72];
    __shared__ __align__(16) bf16 Vts1[64][72];

    const int t    = threadIdx.x;
    const int w    = t >> 6;
    const int lane = t & 63;
    const int quad = lane >> 4;
    const int c    = lane & 15;
    const int q0   = blockIdx.x * 64;
    const int bh   = blockIdx.y;
    const int h    = bh % H_;
    const int b    = bh / H_;
    const size_t base  = (size_t)bh * L_ * D_;
    const size_t vbase = (size_t)bh * D_ * L_;
    const int qrow = q0 + w * 16 + c;      // this lane's q index (column of S^T)

    const float FMAX = expf(fminf(sml[h], MAXLOG)) + 8.0f;

    // Q B-fragments straight from global, held for the whole sweep.
    bf16x8 qf[2];
    qf[0] = *(const bf16x8*)&q[base + (size_t)qrow * D_ + quad * 8];
    qf[1] = *(const bf16x8*)&q[base + (size_t)qrow * D_ + 32 + quad * 8];

    // staging indices (coalesced b128)
    const int r0  = t >> 3,         c00 = (t & 7) * 8;
    const int r1  = (t + 256) >> 3, c01 = ((t + 256) & 7) * 8;

    const size_t brow = (size_t)qrow * L_ + 4 * quad;

    float l_acc = 0.f;
    f32x4 o[4];
    #pragma unroll
    for (int dt = 0; dt < 4; ++dt) o[dt] = (f32x4){0.f, 0.f, 0.f, 0.f};

    bf16x8 kreg[2], vreg[2];
    f32x4  bregA[4], bregB[4];

    // prologue: tile 0 -> regs -> LDS buf0; tile 1 -> regs; bias 0/1 -> regs
    kreg[0] = *(const bf16x8*)&k [base  + (size_t)r0 * D_ + c00];
    kreg[1] = *(const bf16x8*)&k [base  + (size_t)r1 * D_ + c01];
    vreg[0] = *(const bf16x8*)&vt[vbase + (size_t)r0 * L_ + c00];
    vreg[1] = *(const bf16x8*)&vt[vbase + (size_t)r1 * L_ + c01];
    #pragma unroll
    for (int s = 0; s < 4; ++s)
        bregA[s] = *(const f32x4*)&bias[brow + 16 * s];

    *(bf16x8*)&Ks0 [r0][c00] = kreg[0];
    *(bf16x8*)&Ks0 [r1][c01] = kreg[1];
    *(bf16x8*)&Vts0[r0][c00] = vreg[0];
    *(bf16x8*)&Vts0[r1][c01] = vreg[1];

    kreg[0] = *(const bf16x8*)&k [base  + (size_t)(64 + r0) * D_ + c00];
    kreg[1] = *(const bf16x8*)&k [base  + (size_t)(64 + r1) * D_ + c01];
    vreg[0] = *(const bf16x8*)&vt[vbase + (size_t)r0 * L_ + 64 + c00];
    vreg[1] = *(const bf16x8*)&vt[vbase + (size_t)r1 * L_ + 64 + c01];
    #pragma unroll
    for (int s = 0; s < 4; ++s)
        bregB[s] = *(const f32x4*)&bias[brow + 64 + 16 * s];
    __syncthreads();

// One 64-k tile: stage tile IT+1 from regs, prefetch tile IT+2 into regs,
// compute tile IT, single barrier at the end.
#define FSTEP(KS_C, VT_C, KS_N, VT_N, BC, IT) do {                               \
    if ((IT) + 1 < 32) {                                                         \
        *(bf16x8*)&KS_N [r0][c00] = kreg[0];                                     \
        *(bf16x8*)&KS_N [r1][c01] = kreg[1];                                     \
        *(bf16x8*)&VT_N [r0][c00] = vreg[0];                                     \
        *(bf16x8*)&VT_N [r1][c01] = vreg[1];                                     \
    }                                                                            \
    f32x4 st[4];                                                                 \
    _Pragma("unroll") for (int s = 0; s < 4; ++s) st[s] = BC[s];                 \
    if ((IT) + 2 < 32) {                                                         \
        const int kp = ((IT) + 2) * 64;                                          \
        kreg[0] = *(const bf16x8*)&k [base  + (size_t)(kp + r0) * D_ + c00];     \
        kreg[1] = *(const bf16x8*)&k [base  + (size_t)(kp + r1) * D_ + c01];     \
        vreg[0] = *(const bf16x8*)&vt[vbase + (size_t)r0 * L_ + kp + c00];       \
        vreg[1] = *(const bf16x8*)&vt[vbase + (size_t)r1 * L_ + kp + c01];       \
        _Pragma("unroll") for (int s = 0; s < 4; ++s)                            \
            BC[s] = *(const f32x4*)&bias[brow + kp + 16 * s];                    \
    }                                                                            \
    _Pragma("unroll") for (int ks = 0; ks < 2; ++ks)                             \
        _Pragma("unroll") for (int s = 0; s < 4; ++s) {                          \
            const bf16x8 kf = *(const bf16x8*)&KS_C[s*16 + c][ks*32 + quad*8];   \
            st[s] = __builtin_amdgcn_mfma_f32_16x16x32_bf16(kf, qf[ks], st[s], 0, 0, 0); \
        }                                                                        \
    bf16x4 pf[4];                                                                \
    _Pragma("unroll") for (int s = 0; s < 4; ++s)                                \
        _Pragma("unroll") for (int r = 0; r < 4; ++r) {                          \
            const float pv = __expf(st[s][r] - FMAX);                            \
            l_acc += pv;                                                         \
            pf[s][r] = (bf16)pv;                                                 \
        }                                                                        \
    _Pragma("unroll") for (int s = 0; s < 4; ++s)                                \
        _Pragma("unroll") for (int dt = 0; dt < 4; ++dt) {                       \
            const bf16x4 vfr = *(const bf16x4*)&VT_C[dt*16 + c][16*s + 4*quad];  \
            o[dt] = mfma16(vfr, pf[s], o[dt]);                                   \
        }                                                                        \
    __syncthreads();                                                             \
} while (0)

    for (int it = 0; it < 32; it += 2) {
        FSTEP(Ks0, Vts0, Ks1, Vts1, bregA, it);
        FSTEP(Ks1, Vts1, Ks0, Vts0, bregB, it + 1);
    }
#undef FSTEP

    // l: lane holds k-rows 4*quad+0..3 of every tile; reduce across quads.
    float rs = l_acc;
    rs += __shfl_xor(rs, 16);
    rs += __shfl_xor(rs, 32);
    const float linv = 1.0f / rs;

    const size_t obase = ((size_t)(b * L_ + qrow)) * C_ + h * 64;
    #pragma unroll
    for (int dt = 0; dt < 4; ++dt) {
        f16x4 hv, lv;
        #pragma unroll
        for (int r = 0; r < 4; ++r) {
            const float v = o[dt][r] * linv;
            hv[r] = (f16)v;
            lv[r] = (f16)(v - (float)hv[r]);
        }
        *(f16x4*)&aoh[obase + dt * 16 + 4 * quad] = hv;
        *(f16x4*)&aol[obase + dt * 16 + 4 * quad] = lv;
    }
}

// ---------------------------------------------------------------------------
// Kernel 3: projection GEMM v3 — f16 path, 2 MFMAs per output:
//   A = f16 hi/lo pair (22-bit, MORE precise than old bf16 pair),
//   W = single f16 (2^-11 rel; contributes ~4e-5 RMS — negligible vs 4.88e-4).
//   Per k-step: 10 stage16 (was 12), 16 MFMAs/wave (was 24). BM=128 BN=64.
// ---------------------------------------------------------------------------
__global__ __launch_bounds__(256) void proj_mfma(
    const f16* __restrict__ Ahg, const f16* __restrict__ Alg,
    const f16* __restrict__ Wfg,
    const float* __restrict__ bias, float* __restrict__ outp)
{
    __shared__ __align__(16) f16 Ah[128][64];   // 16 KB
    __shared__ __align__(16) f16 Al[128][64];   // 16 KB
    __shared__ __align__(16) f16 Wf[64][64];    //  8 KB

    const int t    = threadIdx.x;
    const int w    = t >> 6;
    const int lane = t & 63;
    const int quad = lane >> 4;
    const int c    = lane & 15;
    const int m0   = blockIdx.x * 128;
    const int n0   = blockIdx.y * 64;

    const int sr = t >> 3;           // 0..31
    const int sc = t & 7;
    const int sx = sc ^ (sr & 7);

    f32x4 acc[2][4];
    #pragma unroll
    for (int mt = 0; mt < 2; ++mt)
        #pragma unroll
        for (int nt = 0; nt < 4; ++nt) acc[mt][nt] = (f32x4){0.f,0.f,0.f,0.f};

    for (int kt = 0; kt < C_; kt += 64) {
        __syncthreads();
        #pragma unroll
        for (int p = 0; p < 4; ++p) {
            const size_t ga = (size_t)(m0 + 32 * p + sr) * C_ + kt + 8 * sx;
            const int    lo = (p * 256 + t) * 16;
            stage16(&Ahg[ga], (char*)&Ah[0][0] + lo);
            stage16(&Alg[ga], (char*)&Al[0][0] + lo);
        }
        #pragma unroll
        for (int p = 0; p < 2; ++p) {
            const size_t gb = (size_t)(n0 + 32 * p + sr) * C_ + kt + 8 * sx;
            const int    lo = (p * 256 + t) * 16;
            stage16(&Wfg[gb], (char*)&Wf[0][0] + lo);
        }
        __syncthreads();

        #pragma unroll
        for (int ks = 0; ks < 2; ++ks) {
            const int rchunk = ((4 * ks + quad) ^ (c & 7)) * 16;
            f16x8 wf[4];
            #pragma unroll
            for (int nt = 0; nt < 4; ++nt)
                wf[nt] = *(const f16x8*)((const char*)&Wf[0][0]
                         + (size_t)(nt * 16 + c) * 128 + rchunk);
            #pragma unroll
            for (int mt = 0; mt < 2; ++mt) {
                const f16x8 ah = *(const f16x8*)((const char*)&Ah[0][0]
                                 + (size_t)(w * 32 + mt * 16 + c) * 128 + rchunk);
                const f16x8 al = *(const f16x8*)((const char*)&Al[0][0]
                                 + (size_t)(w * 32 + mt * 16 + c) * 128 + rchunk);
                #pragma unroll
                for (int nt = 0; nt < 4; ++nt) {
                    acc[mt][nt] = __builtin_amdgcn_mfma_f32_16x16x32_f16(ah, wf[nt], acc[mt][nt], 0, 0, 0);
                    acc[mt][nt] = __builtin_amdgcn_mfma_f32_16x16x32_f16(al, wf[nt], acc[mt][nt], 0, 0, 0);
                }
            }
        }
    }

    #pragma unroll
    for (int mt = 0; mt < 2; ++mt)
        #pragma unroll
        for (int nt = 0; nt < 4; ++nt) {
            const int col = n0 + nt * 16 + c;
            const float bb = bias[col];
            #pragma unroll
            for (int reg = 0; reg < 4; ++reg) {
                const int row = m0 + w * 32 + mt * 16 + quad * 4 + reg;
                outp[(size_t)row * C_ + col] = acc[mt][nt][reg] + bb;
            }
        }
}

// ---------------------------------------------------------------------------
extern "C" void kernel_launch(void* const* d_in, const int* in_sizes, int n_in,
                              void* d_out, int out_size, void* d_ws, size_t ws_size,
                              hipStream_t stream)
{
    const float* x         = (const float*)d_in[0];
    const float* attn_bias = (const float*)d_in[1];
    const float* W_qkv     = (const float*)d_in[2];
    const float* b_qkv     = (const float*)d_in[3];
    const float* sml       = (const float*)d_in[4];
    const float* W_proj    = (const float*)d_in[5];
    const float* b_proj    = (const float*)d_in[6];
    float* out = (float*)d_out;

    // ws layout (2-byte elements): qb,kb,vtb | aoh,aol (f16) | Wf (f16) | pad | xb | wqb
    bf16* qb  = (bf16*)d_ws;
    bf16* kb  = qb  + SZ_;
    bf16* vtb = kb  + SZ_;
    f16*  aoh = (f16*)(vtb + SZ_);
    f16*  aol = aoh + MC_;
    f16*  Wf  = aol + MC_;
    bf16* xb  = (bf16*)(Wf + 2 * WP_);   // (second WP_ slot unused, kept for layout stability)
    bf16* wqb = xb  + MC_;

    // 0) fused prep: cvt x/W_qkv to bf16, W_proj to single f16
    prep<<<2048, 256, 0, stream>>>(
        (const float4*)x, (const float4*)W_qkv, (const float4*)W_proj,
        xb, wqb, Wf);

    // 1) QKV GEMM v2: 128x128 tile (2 heads/block), grid 32x18
    qkv_mfma<<<dim3(M_ / 128, (3 * C_) / 128), 256, 0, stream>>>(
        xb, wqb, b_qkv, sml, qb, kb, vtb);

    // 2) flash attention (v7 structure; f16 hi/lo epilogue)
    flash_mfma<<<dim3(L_ / 64, B_ * H_), 256, 0, stream>>>(
        qb, kb, vtb, attn_bias, sml, aoh, aol);

    // 3) projection GEMM v3: f16 2-MFMA path, BM=128 BN=64, grid 32x12
    proj_mfma<<<dim3(M_ / 128, C_ / 64), 256, 0, stream>>>(
        aoh, aol, Wf, b_proj, out);
}